// Round 6
// baseline (219.973 us; speedup 1.0000x reference)
//
#include <hip/hip_runtime.h>

typedef __attribute__((ext_vector_type(4))) float f32x4;
typedef __attribute__((ext_vector_type(8))) short s16x8;
typedef __attribute__((ext_vector_type(4))) short s16x4;
typedef __bf16 bf16x4 __attribute__((ext_vector_type(4)));

#define B_   96
#define NQ   35
#define LP   180
#define H_   768
#define D_   128
#define NEGF (-1e30f)

#define NROWS 37920
#define QROWS 3360
#define PROWS 17280

__device__ __forceinline__ unsigned short f2bf(float f) {
    return __builtin_bit_cast(unsigned short, (__bf16)f);
}

__device__ __forceinline__ void cvt_hilo(f32x4 v0, f32x4 v1, s16x8* hi, s16x8* lo) {
    bf16x4 h0 = __builtin_convertvector(v0, bf16x4);
    bf16x4 h1 = __builtin_convertvector(v1, bf16x4);
    f32x4 r0 = v0 - __builtin_convertvector(h0, f32x4);
    f32x4 r1 = v1 - __builtin_convertvector(h1, f32x4);
    bf16x4 l0 = __builtin_convertvector(r0, bf16x4);
    bf16x4 l1 = __builtin_convertvector(r1, bf16x4);
    s16x4 h0s = __builtin_bit_cast(s16x4, h0), h1s = __builtin_bit_cast(s16x4, h1);
    s16x4 l0s = __builtin_bit_cast(s16x4, l0), l1s = __builtin_bit_cast(s16x4, l1);
    *hi = __builtin_shufflevector(h0s, h1s, 0, 1, 2, 3, 4, 5, 6, 7);
    *lo = __builtin_shufflevector(l0s, l1s, 0, 1, 2, 3, 4, 5, 6, 7);
}

__device__ __forceinline__ s16x8 pack_bf16(f32x4 v0, f32x4 v1) {
    bf16x4 h0 = __builtin_convertvector(v0, bf16x4);
    bf16x4 h1 = __builtin_convertvector(v1, bf16x4);
    s16x4 a = __builtin_bit_cast(s16x4, h0), b = __builtin_bit_cast(s16x4, h1);
    return __builtin_shufflevector(a, b, 0, 1, 2, 3, 4, 5, 6, 7);
}

// ---------------- prep: wt_build (blocks 0-47) + ssq zero (48-191) + mask detect (192) ----
__global__ __launch_bounds__(256) void prep_k(
    const float* __restrict__ W, unsigned short* __restrict__ wthi,
    const unsigned int* __restrict__ pmask_w, unsigned int* __restrict__ ctrl,
    float* __restrict__ ssq) {
    __shared__ unsigned int rr[256];
    int b = blockIdx.x, t = threadIdx.x;
    if (b < 48) {
        int tid = b * 256 + t;
        int nt = tid / (24 * 64);
        int r = tid - nt * 24 * 64;
        int ks = r / 64, lane = r - ks * 64;
        int m = lane & 15, quad = lane >> 4;
        unsigned short* o = wthi + (size_t)tid * 8;
#pragma unroll
        for (int j = 0; j < 8; j++) {
            int k = ks * 32 + quad * 8 + j;
            o[j] = f2bf(W[(size_t)k * D_ + nt * 16 + m]);
        }
    } else if (b < 192) {
        ssq[(b - 48) * 256 + t] = 0.f;       // 144*256 = 36864 exactly
    } else {
        unsigned int f1 = 0, f3 = 0, f4 = 0;
        for (int w = t; w < 4320; w += 256) {
            unsigned int v = pmask_w[w];
            f1 |= v & 0x0000ff00u;                 // byte %4==1 -> 1-byte layout
            f3 |= v & 0xff000000u;                 // byte %4==3 -> float32
            if (w & 1) f4 |= v & 0x000000ffu;      // byte %8==4 -> int32
        }
        rr[t] = f1; __syncthreads();
        for (int s2 = 128; s2; s2 >>= 1) { if (t < s2) rr[t] |= rr[t + s2]; __syncthreads(); }
        if (!t) ctrl[0] = rr[0];
        __syncthreads();
        rr[t] = f3; __syncthreads();
        for (int s2 = 128; s2; s2 >>= 1) { if (t < s2) rr[t] |= rr[t + s2]; __syncthreads(); }
        if (!t) ctrl[1] = rr[0];
        __syncthreads();
        rr[t] = f4; __syncthreads();
        for (int s2 = 128; s2; s2 >>= 1) { if (t < s2) rr[t] |= rr[t + s2]; __syncthreads(); }
        if (!t) ctrl[2] = rr[0];
    }
}

// ---------------- proj: block = 16-row group, 4 waves = K-quarters, LDS combine ----------
// A-loads fully hoisted (12 KB/wave in flight) so the A stream is BW-bound, not
// round-trip-latency-bound. Epilogue fuses sequence-axis sum-of-squares (atomicAdd ssq).
__global__ __launch_bounds__(256) void proj_k(
    const float* __restrict__ qh, const float* __restrict__ ph, const float* __restrict__ nh,
    const unsigned short* __restrict__ wthi, const float* __restrict__ bias,
    float* __restrict__ x, float* __restrict__ ssq,
    const void* __restrict__ pm, const void* __restrict__ nm,
    const unsigned int* __restrict__ ctrl, unsigned char* __restrict__ maskc) {
    __shared__ f32x4 part[4][8][64];                 // 32 KB
    int b = blockIdx.x;
    if (b >= 2370) {                                 // ---- mask canon: 135 blocks exact ----
        int i = (b - 2370) * 256 + threadIdx.x;      // < 34560
        const void* src = (i < B_ * LP) ? pm : nm;
        int j = (i < B_ * LP) ? i : i - B_ * LP;
        unsigned int c1 = ctrl[0], c3 = ctrl[1], c4 = ctrl[2];
        bool bit;
        if (c1 > 0)       bit = ((const unsigned char*)src)[j] != 0;
        else if (c3 > 0)  bit = ((const float*)src)[j] != 0.0f;
        else if (c4 > 0)  bit = ((const int*)src)[j] != 0;
        else              bit = ((const long long*)src)[j] != 0;
        maskc[i] = bit ? 1 : 0;
        return;
    }
    int wave = threadIdx.x >> 6, lane = threadIdx.x & 63;
    int rg = b;
    const float* src; int row0l; int growbase;
    if (rg < 210)       { src = qh; row0l = rg * 16;          growbase = row0l; }
    else if (rg < 1290) { src = ph; row0l = (rg - 210) * 16;  growbase = QROWS + row0l; }
    else                { src = nh; row0l = (rg - 1290) * 16; growbase = QROWS + PROWS + row0l; }
    int m = lane & 15, quad = lane >> 4;
    const float* ap = src + (size_t)(row0l + m) * H_ + wave * 192 + quad * 8;

    // hoist ALL A loads (12 x f32x4 = 12 KB/wave outstanding)
    f32x4 av[12];
#pragma unroll
    for (int kl = 0; kl < 6; kl++) {
        const f32x4* pA = (const f32x4*)(ap + kl * 32);
        av[2 * kl]     = pA[0];
        av[2 * kl + 1] = pA[1];
    }

    f32x4 acc[8];
#pragma unroll
    for (int nt = 0; nt < 8; nt++) acc[nt] = (f32x4){0.f, 0.f, 0.f, 0.f};

#pragma unroll
    for (int kl = 0; kl < 6; kl++) {
        s16x8 ahi, alo;
        cvt_hilo(av[2 * kl], av[2 * kl + 1], &ahi, &alo);
        int ksg = wave * 6 + kl;
        s16x8 bh[8];
#pragma unroll
        for (int nt = 0; nt < 8; nt++)
            bh[nt] = *(const s16x8*)(wthi + ((size_t)(nt * 24 + ksg) * 64 + lane) * 8);
#pragma unroll
        for (int nt = 0; nt < 8; nt++) {
            acc[nt] = __builtin_amdgcn_mfma_f32_16x16x32_bf16(ahi, bh[nt], acc[nt], 0, 0, 0);
            acc[nt] = __builtin_amdgcn_mfma_f32_16x16x32_bf16(alo, bh[nt], acc[nt], 0, 0, 0);
        }
    }
#pragma unroll
    for (int nt = 0; nt < 8; nt++) part[wave][nt][lane] = acc[nt];
    __syncthreads();

    // batch mapping for this 16-row group (at most 2 batches)
    int bk0, bk1, b1start;
    if (growbase < QROWS)              { bk0 = growbase / 35;  bk1 = (growbase + 15) / 35;
                                         b1start = bk1 * 35; }
    else if (growbase < QROWS + PROWS) { int r0 = growbase - QROWS;
                                         bk0 = 96 + r0 / 180;  bk1 = 96 + (r0 + 15) / 180;
                                         b1start = QROWS + (bk1 - 96) * 180; }
    else                               { int r0 = growbase - QROWS - PROWS;
                                         bk0 = 192 + r0 / 180; bk1 = 192 + (r0 + 15) / 180;
                                         b1start = QROWS + PROWS + (bk1 - 192) * 180; }

#pragma unroll
    for (int q2 = 0; q2 < 2; q2++) {
        int nt = wave * 2 + q2;
        f32x4 s = part[0][nt][lane];
        s += part[1][nt][lane];
        s += part[2][nt][lane];
        s += part[3][nt][lane];
        int col = nt * 16 + m;
        float bv = bias[col];
        float slo = 0.f, shi = 0.f;
#pragma unroll
        for (int r = 0; r < 4; r++) {
            int grow = growbase + quad * 4 + r;
            float v = s[r] + bv;
            x[(size_t)grow * D_ + col] = v;
            float v2 = v * v;
            if (bk1 > bk0 && grow >= b1start) shi += v2; else slo += v2;
        }
        slo += __shfl_xor(slo, 16); slo += __shfl_xor(slo, 32);
        if (quad == 0) atomicAdd(ssq + (size_t)bk0 * D_ + col, slo);
        if (bk1 > bk0) {
            shi += __shfl_xor(shi, 16); shi += __shfl_xor(shi, 32);
            if (quad == 0) atomicAdd(ssq + (size_t)bk1 * D_ + col, shi);
        }
    }
}

// ---------------- scale + bf16 + scatter: one thread per 16B frag chunk -----------------
// chunk index c: qfrag region c<61440: c = ((qp*5+mt)<<8)|(ks<<6)|lane;
// pfrag region: c2 = ((pbk*12+nt)<<8)|(ks<<6)|lane. Each thread reads 8 consecutive d of
// one x row, scales by rsqrt(ssq), packs s16x8, one coalesced 16B store.
// Invalid/pad p-rows get token 0 of the same passage (mask[:,0] always True) -> interact
// is mask-free. q pad rows (prow>=70) written as zeros.
__global__ __launch_bounds__(256) void scatter_k(
    const float* __restrict__ x, const float* __restrict__ ssq,
    const unsigned char* __restrict__ maskc,
    unsigned short* __restrict__ qfrag, unsigned short* __restrict__ pfrag) {
    int c = blockIdx.x * 256 + threadIdx.x;          // 651264 total = 2544*256
    int lane = c & 63, ks = (c >> 6) & 3;
    int quad = lane >> 4, mm = lane & 15;
    int d0 = ks * 32 + quad * 8;
    if (c < 61440) {
        int g = c >> 8;                              // qp*5 + mt
        int mt = g % 5, qp = g / 5;
        int prow = mt * 16 + mm;
        s16x8 outv = (s16x8){0, 0, 0, 0, 0, 0, 0, 0};
        if (prow < 70) {
            int hi = prow >= 35;
            int bq = qp * 2 + hi;
            int l = prow - hi * 35;
            size_t row = (size_t)bq * 35 + l;
            const f32x4* px = (const f32x4*)(x + row * D_ + d0);
            f32x4 v0 = px[0], v1 = px[1];
            const f32x4* pq = (const f32x4*)(ssq + (size_t)bq * D_ + d0);
            f32x4 q0 = pq[0], q1 = pq[1];
            f32x4 r0, r1;
#pragma unroll
            for (int j = 0; j < 4; j++) {
                r0[j] = rsqrtf(fmaxf(q0[j], 1e-24f));
                r1[j] = rsqrtf(fmaxf(q1[j], 1e-24f));
            }
            outv = pack_bf16(v0 * r0, v1 * r1);
        }
        *(s16x8*)(qfrag + (size_t)c * 8) = outv;
    } else {
        int c2 = c - 61440;
        int g = c2 >> 8;                             // pbk*12 + nt
        int nt = g % 12, pbk = g / 12;
        int l = nt * 16 + mm;
        int lsrc = (l < LP && maskc[pbk * LP + l]) ? l : 0;
        size_t row = QROWS + (size_t)pbk * LP + lsrc;
        const f32x4* px = (const f32x4*)(x + row * D_ + d0);
        f32x4 v0 = px[0], v1 = px[1];
        const f32x4* pq = (const f32x4*)(ssq + (size_t)(96 + pbk) * D_ + d0);
        f32x4 q0 = pq[0], q1 = pq[1];
        f32x4 r0, r1;
#pragma unroll
        for (int j = 0; j < 4; j++) {
            r0[j] = rsqrtf(fmaxf(q0[j], 1e-24f));
            r1[j] = rsqrtf(fmaxf(q1[j], 1e-24f));
        }
        *(s16x8*)(pfrag + (size_t)c2 * 8) = pack_bf16(v0 * r0, v1 * r1);
    }
}

// ---------------- late interaction: mask-free, XCD-pinned, direct L2 loads -------------
__global__ __launch_bounds__(256, 3) void interact_k(
    const unsigned short* __restrict__ qfrag, const unsigned short* __restrict__ pfrag,
    float* __restrict__ out) {
    int wave = threadIdx.x >> 6, lane = threadIdx.x & 63;
    int b = blockIdx.x;                              // 2304 blocks
    int xcd = b & 7, i = b >> 3;                     // i in [0,288)
    int c = xcd * 24 + (i % 24);                     // [0,192)
    int qg = i / 24;                                 // [0,12)
    int side = c / 96, pb = c - side * 96;
    int qp = qg * 4 + wave;
    int m = lane & 15, quad = lane >> 4;

    const unsigned short* pbase = pfrag + (size_t)c * 24576;
    const unsigned short* qbase = qfrag + (size_t)qp * 10240;

    s16x8 a[5][4];
#pragma unroll
    for (int mt = 0; mt < 5; mt++)
#pragma unroll
        for (int ks = 0; ks < 4; ks++)
            a[mt][ks] = *(const s16x8*)(qbase + ((size_t)(mt * 4 + ks) * 64 + lane) * 8);

    const f32x4 zero4 = (f32x4){0.f, 0.f, 0.f, 0.f};
    float rmax[5][4];
#pragma unroll
    for (int mt = 0; mt < 5; mt++)
#pragma unroll
        for (int rr = 0; rr < 4; rr++) rmax[mt][rr] = NEGF;

    for (int nt = 0; nt < 12; nt++) {
        s16x8 bfr[4];
#pragma unroll
        for (int ks = 0; ks < 4; ks++)
            bfr[ks] = *(const s16x8*)(pbase + ((size_t)(nt * 4 + ks) * 64 + lane) * 8);
#pragma unroll
        for (int mt = 0; mt < 5; mt++) {
            f32x4 acc = __builtin_amdgcn_mfma_f32_16x16x32_bf16(a[mt][0], bfr[0], zero4, 0, 0, 0);
            acc = __builtin_amdgcn_mfma_f32_16x16x32_bf16(a[mt][1], bfr[1], acc, 0, 0, 0);
            acc = __builtin_amdgcn_mfma_f32_16x16x32_bf16(a[mt][2], bfr[2], acc, 0, 0, 0);
            acc = __builtin_amdgcn_mfma_f32_16x16x32_bf16(a[mt][3], bfr[3], acc, 0, 0, 0);
#pragma unroll
            for (int rr = 0; rr < 4; rr++)
                rmax[mt][rr] = fmaxf(rmax[mt][rr], acc[rr]);
        }
    }

#pragma unroll
    for (int mt = 0; mt < 5; mt++)
#pragma unroll
        for (int rr = 0; rr < 4; rr++) {
            float v = rmax[mt][rr];
            v = fmaxf(v, __shfl_xor(v, 1));
            v = fmaxf(v, __shfl_xor(v, 2));
            v = fmaxf(v, __shfl_xor(v, 4));
            v = fmaxf(v, __shfl_xor(v, 8));
            rmax[mt][rr] = v;
        }
    float s0 = 0.f, s1 = 0.f;
#pragma unroll
    for (int mt = 0; mt < 5; mt++)
#pragma unroll
        for (int rr = 0; rr < 4; rr++) {
            int prow = mt * 16 + quad * 4 + rr;
            float v = rmax[mt][rr];
            if (prow < 35) s0 += v;
            else if (prow < 70) s1 += v;
        }
    s0 += __shfl_xor(s0, 16); s0 += __shfl_xor(s0, 32);
    s1 += __shfl_xor(s1, 16); s1 += __shfl_xor(s1, 32);
    if (lane == 0) {
        int qb0 = qp * 2, qb1 = qp * 2 + 1;
        out[(size_t)qb0 * (2 * B_) + side * B_ + pb] = s0;
        out[(size_t)qb1 * (2 * B_) + side * B_ + pb] = s1;
    }
}

// ---------------- launch ----------------
extern "C" void kernel_launch(void* const* d_in, const int* in_sizes, int n_in,
                              void* d_out, int out_size, void* d_ws, size_t ws_size,
                              hipStream_t stream) {
    const float* qh   = (const float*)d_in[0];
    const float* ph   = (const float*)d_in[1];
    const float* nh   = (const float*)d_in[2];
    const float* W    = (const float*)d_in[3];
    const float* bias = (const float*)d_in[4];
    const void* pmask = d_in[5];
    const void* nmask = d_in[6];
    float* out = (float*)d_out;
    char* ws = (char*)d_ws;

    constexpr size_t CTRL_OFF  = 0;                          // 256 B
    constexpr size_t WTHI_OFF  = 256;                        // 196608 B
    constexpr size_t MASKC_OFF = WTHI_OFF + 196608;          // 34560 B -> ends 231424
    constexpr size_t SSQ_OFF   = 231424;                     // 147456 B
    constexpr size_t X_OFF     = SSQ_OFF + 147456;           // 19415040 B
    constexpr size_t QFRAG_OFF = X_OFF + (size_t)NROWS * D_ * 4;   // 983040 B
    constexpr size_t PFRAG_OFF = QFRAG_OFF + 983040;         // 9437184 B

    unsigned int* ctrl     = (unsigned int*)(ws + CTRL_OFF);
    unsigned short* wthi   = (unsigned short*)(ws + WTHI_OFF);
    unsigned char* maskc   = (unsigned char*)(ws + MASKC_OFF);
    float* ssq             = (float*)(ws + SSQ_OFF);
    float* x               = (float*)(ws + X_OFF);
    unsigned short* qfrag  = (unsigned short*)(ws + QFRAG_OFF);
    unsigned short* pfrag  = (unsigned short*)(ws + PFRAG_OFF);

    prep_k<<<193, 256, 0, stream>>>(W, wthi, (const unsigned int*)pmask, ctrl, ssq);
    proj_k<<<2370 + 135, 256, 0, stream>>>(qh, ph, nh, wthi, bias, x, ssq,
                                           pmask, nmask, ctrl, maskc);
    scatter_k<<<2544, 256, 0, stream>>>(x, ssq, maskc, qfrag, pfrag);
    interact_k<<<2304, 256, 0, stream>>>(qfrag, pfrag, out);
}

// Round 7
// 214.034 us; speedup vs baseline: 1.0277x; 1.0277x over previous
//
#include <hip/hip_runtime.h>

typedef __attribute__((ext_vector_type(4))) float f32x4;
typedef __attribute__((ext_vector_type(8))) short s16x8;
typedef __attribute__((ext_vector_type(4))) short s16x4;
typedef __bf16 bf16x4 __attribute__((ext_vector_type(4)));

#define B_   96
#define NQ   35
#define LP   180
#define H_   768
#define D_   128
#define NEGF (-1e30f)

#define NROWS 37920
#define QROWS 3360
#define PROWS 17280

__device__ __forceinline__ unsigned short f2bf(float f) {
    return __builtin_bit_cast(unsigned short, (__bf16)f);
}

__device__ __forceinline__ void cvt_hilo(f32x4 v0, f32x4 v1, s16x8* hi, s16x8* lo) {
    bf16x4 h0 = __builtin_convertvector(v0, bf16x4);
    bf16x4 h1 = __builtin_convertvector(v1, bf16x4);
    f32x4 r0 = v0 - __builtin_convertvector(h0, f32x4);
    f32x4 r1 = v1 - __builtin_convertvector(h1, f32x4);
    bf16x4 l0 = __builtin_convertvector(r0, bf16x4);
    bf16x4 l1 = __builtin_convertvector(r1, bf16x4);
    s16x4 h0s = __builtin_bit_cast(s16x4, h0), h1s = __builtin_bit_cast(s16x4, h1);
    s16x4 l0s = __builtin_bit_cast(s16x4, l0), l1s = __builtin_bit_cast(s16x4, l1);
    *hi = __builtin_shufflevector(h0s, h1s, 0, 1, 2, 3, 4, 5, 6, 7);
    *lo = __builtin_shufflevector(l0s, l1s, 0, 1, 2, 3, 4, 5, 6, 7);
}

__device__ __forceinline__ s16x8 pack_bf16(f32x4 v0, f32x4 v1) {
    bf16x4 h0 = __builtin_convertvector(v0, bf16x4);
    bf16x4 h1 = __builtin_convertvector(v1, bf16x4);
    s16x4 a = __builtin_bit_cast(s16x4, h0), b = __builtin_bit_cast(s16x4, h1);
    return __builtin_shufflevector(a, b, 0, 1, 2, 3, 4, 5, 6, 7);
}

// async global->LDS, 16 B per lane; lds dest must be wave-uniform (HW adds lane*16)
__device__ __forceinline__ void glds16(const void* g, void* l) {
    __builtin_amdgcn_global_load_lds(
        (const __attribute__((address_space(1))) unsigned int*)g,
        (__attribute__((address_space(3))) unsigned int*)l,
        16, 0, 0);
}

// ---------------- prep: wt_build (blocks 0-47) + ssq zero (48-191) + mask detect (192) ----
__global__ __launch_bounds__(256) void prep_k(
    const float* __restrict__ W, unsigned short* __restrict__ wthi,
    const unsigned int* __restrict__ pmask_w, unsigned int* __restrict__ ctrl,
    float* __restrict__ ssq) {
    __shared__ unsigned int rr[256];
    int b = blockIdx.x, t = threadIdx.x;
    if (b < 48) {
        int tid = b * 256 + t;
        int nt = tid / (24 * 64);
        int r = tid - nt * 24 * 64;
        int ks = r / 64, lane = r - ks * 64;
        int m = lane & 15, quad = lane >> 4;
        unsigned short* o = wthi + (size_t)tid * 8;
#pragma unroll
        for (int j = 0; j < 8; j++) {
            int k = ks * 32 + quad * 8 + j;
            o[j] = f2bf(W[(size_t)k * D_ + nt * 16 + m]);
        }
    } else if (b < 192) {
        ssq[(b - 48) * 256 + t] = 0.f;       // 144*256 = 36864 exactly
    } else {
        unsigned int f1 = 0, f3 = 0, f4 = 0;
        for (int w = t; w < 4320; w += 256) {
            unsigned int v = pmask_w[w];
            f1 |= v & 0x0000ff00u;                 // byte %4==1 -> 1-byte layout
            f3 |= v & 0xff000000u;                 // byte %4==3 -> float32
            if (w & 1) f4 |= v & 0x000000ffu;      // byte %8==4 -> int32
        }
        rr[t] = f1; __syncthreads();
        for (int s2 = 128; s2; s2 >>= 1) { if (t < s2) rr[t] |= rr[t + s2]; __syncthreads(); }
        if (!t) ctrl[0] = rr[0];
        __syncthreads();
        rr[t] = f3; __syncthreads();
        for (int s2 = 128; s2; s2 >>= 1) { if (t < s2) rr[t] |= rr[t + s2]; __syncthreads(); }
        if (!t) ctrl[1] = rr[0];
        __syncthreads();
        rr[t] = f4; __syncthreads();
        for (int s2 = 128; s2; s2 >>= 1) { if (t < s2) rr[t] |= rr[t + s2]; __syncthreads(); }
        if (!t) ctrl[2] = rr[0];
    }
}

// ---------------- proj: block = 16-row group, 4 waves = K-quarters ----------------------
// A-tile (12 KB/wave) staged via async global_load_lds (un-sinkable, no VGPR round trip),
// one barrier drain, compute from LDS. The wave-private A region is reused as the
// K-partial combine buffer. Epilogue fuses sequence-axis sum-of-squares (atomicAdd ssq).
__global__ __launch_bounds__(256) void proj_k(
    const float* __restrict__ qh, const float* __restrict__ ph, const float* __restrict__ nh,
    const unsigned short* __restrict__ wthi, const float* __restrict__ bias,
    float* __restrict__ x, float* __restrict__ ssq,
    const void* __restrict__ pm, const void* __restrict__ nm,
    const unsigned int* __restrict__ ctrl, unsigned char* __restrict__ maskc) {
    __shared__ float abuf[4][3072];                  // 48 KB: per-wave 12 KB A / part buffer
    int b = blockIdx.x;
    if (b >= 2370) {                                 // ---- mask canon: 135 blocks exact ----
        int i = (b - 2370) * 256 + threadIdx.x;      // < 34560
        const void* src = (i < B_ * LP) ? pm : nm;
        int j = (i < B_ * LP) ? i : i - B_ * LP;
        unsigned int c1 = ctrl[0], c3 = ctrl[1], c4 = ctrl[2];
        bool bit;
        if (c1 > 0)       bit = ((const unsigned char*)src)[j] != 0;
        else if (c3 > 0)  bit = ((const float*)src)[j] != 0.0f;
        else if (c4 > 0)  bit = ((const int*)src)[j] != 0;
        else              bit = ((const long long*)src)[j] != 0;
        maskc[i] = bit ? 1 : 0;
        return;
    }
    int wave = threadIdx.x >> 6, lane = threadIdx.x & 63;
    int rg = b;
    const float* src; int row0l; int growbase;
    if (rg < 210)       { src = qh; row0l = rg * 16;          growbase = row0l; }
    else if (rg < 1290) { src = ph; row0l = (rg - 210) * 16;  growbase = QROWS + row0l; }
    else                { src = nh; row0l = (rg - 1290) * 16; growbase = QROWS + PROWS + row0l; }
    int m = lane & 15, quad = lane >> 4;
    const float* ap = src + (size_t)(row0l + m) * H_ + wave * 192 + quad * 8;

    // async-stage the whole A tile: 12 x (64 lanes x 16 B) = 12 KB per wave
#pragma unroll
    for (int kl = 0; kl < 6; kl++) {
        glds16(ap + kl * 32,     &abuf[wave][kl * 512]);
        glds16(ap + kl * 32 + 4, &abuf[wave][kl * 512 + 256]);
    }
    __syncthreads();                                 // drains vmcnt -> LDS valid block-wide

    f32x4 acc[8];
#pragma unroll
    for (int nt = 0; nt < 8; nt++) acc[nt] = (f32x4){0.f, 0.f, 0.f, 0.f};

#pragma unroll
    for (int kl = 0; kl < 6; kl++) {
        f32x4 v0 = *(const f32x4*)&abuf[wave][kl * 512 + lane * 4];
        f32x4 v1 = *(const f32x4*)&abuf[wave][kl * 512 + 256 + lane * 4];
        s16x8 ahi, alo;
        cvt_hilo(v0, v1, &ahi, &alo);
        int ksg = wave * 6 + kl;
        s16x8 bh[8];
#pragma unroll
        for (int nt = 0; nt < 8; nt++)
            bh[nt] = *(const s16x8*)(wthi + ((size_t)(nt * 24 + ksg) * 64 + lane) * 8);
#pragma unroll
        for (int nt = 0; nt < 8; nt++) {
            acc[nt] = __builtin_amdgcn_mfma_f32_16x16x32_bf16(ahi, bh[nt], acc[nt], 0, 0, 0);
            acc[nt] = __builtin_amdgcn_mfma_f32_16x16x32_bf16(alo, bh[nt], acc[nt], 0, 0, 0);
        }
    }
    // write K-partials into the (now-consumed) wave-private A region: part[nt][lane]
#pragma unroll
    for (int nt = 0; nt < 8; nt++)
        *(f32x4*)&abuf[wave][nt * 256 + lane * 4] = acc[nt];
    __syncthreads();

    // batch mapping for this 16-row group (at most 2 batches)
    int bk0, bk1, b1start;
    if (growbase < QROWS)              { bk0 = growbase / 35;  bk1 = (growbase + 15) / 35;
                                         b1start = bk1 * 35; }
    else if (growbase < QROWS + PROWS) { int r0 = growbase - QROWS;
                                         bk0 = 96 + r0 / 180;  bk1 = 96 + (r0 + 15) / 180;
                                         b1start = QROWS + (bk1 - 96) * 180; }
    else                               { int r0 = growbase - QROWS - PROWS;
                                         bk0 = 192 + r0 / 180; bk1 = 192 + (r0 + 15) / 180;
                                         b1start = QROWS + PROWS + (bk1 - 192) * 180; }

#pragma unroll
    for (int q2 = 0; q2 < 2; q2++) {
        int nt = wave * 2 + q2;
        f32x4 s = *(const f32x4*)&abuf[0][nt * 256 + lane * 4];
        s += *(const f32x4*)&abuf[1][nt * 256 + lane * 4];
        s += *(const f32x4*)&abuf[2][nt * 256 + lane * 4];
        s += *(const f32x4*)&abuf[3][nt * 256 + lane * 4];
        int col = nt * 16 + m;
        float bv = bias[col];
        float slo = 0.f, shi = 0.f;
#pragma unroll
        for (int r = 0; r < 4; r++) {
            int grow = growbase + quad * 4 + r;
            float v = s[r] + bv;
            x[(size_t)grow * D_ + col] = v;
            float v2 = v * v;
            if (bk1 > bk0 && grow >= b1start) shi += v2; else slo += v2;
        }
        slo += __shfl_xor(slo, 16); slo += __shfl_xor(slo, 32);
        if (quad == 0) atomicAdd(ssq + (size_t)bk0 * D_ + col, slo);
        if (bk1 > bk0) {
            shi += __shfl_xor(shi, 16); shi += __shfl_xor(shi, 32);
            if (quad == 0) atomicAdd(ssq + (size_t)bk1 * D_ + col, shi);
        }
    }
}

// ---------------- scale + bf16 + scatter: one thread per 16B frag chunk -----------------
__global__ __launch_bounds__(256) void scatter_k(
    const float* __restrict__ x, const float* __restrict__ ssq,
    const unsigned char* __restrict__ maskc,
    unsigned short* __restrict__ qfrag, unsigned short* __restrict__ pfrag) {
    int c = blockIdx.x * 256 + threadIdx.x;          // 651264 total = 2544*256
    int lane = c & 63, ks = (c >> 6) & 3;
    int quad = lane >> 4, mm = lane & 15;
    int d0 = ks * 32 + quad * 8;
    if (c < 61440) {
        int g = c >> 8;                              // qp*5 + mt
        int mt = g % 5, qp = g / 5;
        int prow = mt * 16 + mm;
        s16x8 outv = (s16x8){0, 0, 0, 0, 0, 0, 0, 0};
        if (prow < 70) {
            int hi = prow >= 35;
            int bq = qp * 2 + hi;
            int l = prow - hi * 35;
            size_t row = (size_t)bq * 35 + l;
            const f32x4* px = (const f32x4*)(x + row * D_ + d0);
            f32x4 v0 = px[0], v1 = px[1];
            const f32x4* pq = (const f32x4*)(ssq + (size_t)bq * D_ + d0);
            f32x4 q0 = pq[0], q1 = pq[1];
            f32x4 r0, r1;
#pragma unroll
            for (int j = 0; j < 4; j++) {
                r0[j] = rsqrtf(fmaxf(q0[j], 1e-24f));
                r1[j] = rsqrtf(fmaxf(q1[j], 1e-24f));
            }
            outv = pack_bf16(v0 * r0, v1 * r1);
        }
        *(s16x8*)(qfrag + (size_t)c * 8) = outv;
    } else {
        int c2 = c - 61440;
        int g = c2 >> 8;                             // pbk*12 + nt
        int nt = g % 12, pbk = g / 12;
        int l = nt * 16 + mm;
        int lsrc = (l < LP && maskc[pbk * LP + l]) ? l : 0;
        size_t row = QROWS + (size_t)pbk * LP + lsrc;
        const f32x4* px = (const f32x4*)(x + row * D_ + d0);
        f32x4 v0 = px[0], v1 = px[1];
        const f32x4* pq = (const f32x4*)(ssq + (size_t)(96 + pbk) * D_ + d0);
        f32x4 q0 = pq[0], q1 = pq[1];
        f32x4 r0, r1;
#pragma unroll
        for (int j = 0; j < 4; j++) {
            r0[j] = rsqrtf(fmaxf(q0[j], 1e-24f));
            r1[j] = rsqrtf(fmaxf(q1[j], 1e-24f));
        }
        *(s16x8*)(pfrag + (size_t)c2 * 8) = pack_bf16(v0 * r0, v1 * r1);
    }
}

// ---------------- late interaction: p-block staged via glds, XCD-pinned, mask-free ------
__global__ __launch_bounds__(256, 3) void interact_k(
    const unsigned short* __restrict__ qfrag, const unsigned short* __restrict__ pfrag,
    float* __restrict__ out) {
    __shared__ unsigned short plds[24576];           // 48 KB, shared by all 4 waves
    int wave = threadIdx.x >> 6, lane = threadIdx.x & 63;
    int b = blockIdx.x;                              // 2304 blocks
    int xcd = b & 7, i = b >> 3;                     // i in [0,288)
    int c = xcd * 24 + (i % 24);                     // [0,192)
    int qg = i / 24;                                 // [0,12)
    int side = c / 96, pb = c - side * 96;
    int qp = qg * 4 + wave;
    int m = lane & 15, quad = lane >> 4;

    const unsigned short* pbase = pfrag + (size_t)c * 24576;
    const unsigned short* qbase = qfrag + (size_t)qp * 10240;

    // wave stages its 3 nt-groups: 12 x 1 KB async
#pragma unroll
    for (int ntl = 0; ntl < 3; ntl++) {
        int nt = wave * 3 + ntl;
#pragma unroll
        for (int ks = 0; ks < 4; ks++)
            glds16(pbase + ((size_t)(nt * 4 + ks) * 64 + lane) * 8,
                   &plds[(size_t)(nt * 4 + ks) * 512]);
    }

    s16x8 a[5][4];
#pragma unroll
    for (int mt = 0; mt < 5; mt++)
#pragma unroll
        for (int ks = 0; ks < 4; ks++)
            a[mt][ks] = *(const s16x8*)(qbase + ((size_t)(mt * 4 + ks) * 64 + lane) * 8);

    __syncthreads();                                 // drain staging

    const f32x4 zero4 = (f32x4){0.f, 0.f, 0.f, 0.f};
    float rmax[5][4];
#pragma unroll
    for (int mt = 0; mt < 5; mt++)
#pragma unroll
        for (int rr = 0; rr < 4; rr++) rmax[mt][rr] = NEGF;

    for (int nt = 0; nt < 12; nt++) {
        s16x8 bfr[4];
#pragma unroll
        for (int ks = 0; ks < 4; ks++)
            bfr[ks] = *(const s16x8*)&plds[((size_t)(nt * 4 + ks) * 64 + lane) * 8];
#pragma unroll
        for (int mt = 0; mt < 5; mt++) {
            f32x4 acc = __builtin_amdgcn_mfma_f32_16x16x32_bf16(a[mt][0], bfr[0], zero4, 0, 0, 0);
            acc = __builtin_amdgcn_mfma_f32_16x16x32_bf16(a[mt][1], bfr[1], acc, 0, 0, 0);
            acc = __builtin_amdgcn_mfma_f32_16x16x32_bf16(a[mt][2], bfr[2], acc, 0, 0, 0);
            acc = __builtin_amdgcn_mfma_f32_16x16x32_bf16(a[mt][3], bfr[3], acc, 0, 0, 0);
#pragma unroll
            for (int rr = 0; rr < 4; rr++)
                rmax[mt][rr] = fmaxf(rmax[mt][rr], acc[rr]);
        }
    }

#pragma unroll
    for (int mt = 0; mt < 5; mt++)
#pragma unroll
        for (int rr = 0; rr < 4; rr++) {
            float v = rmax[mt][rr];
            v = fmaxf(v, __shfl_xor(v, 1));
            v = fmaxf(v, __shfl_xor(v, 2));
            v = fmaxf(v, __shfl_xor(v, 4));
            v = fmaxf(v, __shfl_xor(v, 8));
            rmax[mt][rr] = v;
        }
    float s0 = 0.f, s1 = 0.f;
#pragma unroll
    for (int mt = 0; mt < 5; mt++)
#pragma unroll
        for (int rr = 0; rr < 4; rr++) {
            int prow = mt * 16 + quad * 4 + rr;
            float v = rmax[mt][rr];
            if (prow < 35) s0 += v;
            else if (prow < 70) s1 += v;
        }
    s0 += __shfl_xor(s0, 16); s0 += __shfl_xor(s0, 32);
    s1 += __shfl_xor(s1, 16); s1 += __shfl_xor(s1, 32);
    if (lane == 0) {
        int qb0 = qp * 2, qb1 = qp * 2 + 1;
        out[(size_t)qb0 * (2 * B_) + side * B_ + pb] = s0;
        out[(size_t)qb1 * (2 * B_) + side * B_ + pb] = s1;
    }
}

// ---------------- launch ----------------
extern "C" void kernel_launch(void* const* d_in, const int* in_sizes, int n_in,
                              void* d_out, int out_size, void* d_ws, size_t ws_size,
                              hipStream_t stream) {
    const float* qh   = (const float*)d_in[0];
    const float* ph   = (const float*)d_in[1];
    const float* nh   = (const float*)d_in[2];
    const float* W    = (const float*)d_in[3];
    const float* bias = (const float*)d_in[4];
    const void* pmask = d_in[5];
    const void* nmask = d_in[6];
    float* out = (float*)d_out;
    char* ws = (char*)d_ws;

    constexpr size_t CTRL_OFF  = 0;                          // 256 B
    constexpr size_t WTHI_OFF  = 256;                        // 196608 B
    constexpr size_t MASKC_OFF = WTHI_OFF + 196608;          // 34560 B -> ends 231424
    constexpr size_t SSQ_OFF   = 231424;                     // 147456 B
    constexpr size_t X_OFF     = SSQ_OFF + 147456;           // 19415040 B
    constexpr size_t QFRAG_OFF = X_OFF + (size_t)NROWS * D_ * 4;   // 983040 B
    constexpr size_t PFRAG_OFF = QFRAG_OFF + 983040;         // 9437184 B

    unsigned int* ctrl     = (unsigned int*)(ws + CTRL_OFF);
    unsigned short* wthi   = (unsigned short*)(ws + WTHI_OFF);
    unsigned char* maskc   = (unsigned char*)(ws + MASKC_OFF);
    float* ssq             = (float*)(ws + SSQ_OFF);
    float* x               = (float*)(ws + X_OFF);
    unsigned short* qfrag  = (unsigned short*)(ws + QFRAG_OFF);
    unsigned short* pfrag  = (unsigned short*)(ws + PFRAG_OFF);

    prep_k<<<193, 256, 0, stream>>>(W, wthi, (const unsigned int*)pmask, ctrl, ssq);
    proj_k<<<2370 + 135, 256, 0, stream>>>(qh, ph, nh, wthi, bias, x, ssq,
                                           pmask, nmask, ctrl, maskc);
    scatter_k<<<2544, 256, 0, stream>>>(x, ssq, maskc, qfrag, pfrag);
    interact_k<<<2304, 256, 0, stream>>>(qfrag, pfrag, out);
}

// Round 8
// 211.511 us; speedup vs baseline: 1.0400x; 1.0119x over previous
//
#include <hip/hip_runtime.h>

typedef __attribute__((ext_vector_type(4))) float f32x4;
typedef __attribute__((ext_vector_type(8))) short s16x8;
typedef __attribute__((ext_vector_type(4))) short s16x4;
typedef __bf16 bf16x4 __attribute__((ext_vector_type(4)));

#define B_   96
#define NQ   35
#define LP   180
#define H_   768
#define D_   128
#define NEGF (-1e30f)

#define NROWS 37920
#define QROWS 3360
#define PROWS 17280

__device__ __forceinline__ unsigned short f2bf(float f) {
    return __builtin_bit_cast(unsigned short, (__bf16)f);
}

__device__ __forceinline__ void cvt_hilo(f32x4 v0, f32x4 v1, s16x8* hi, s16x8* lo) {
    bf16x4 h0 = __builtin_convertvector(v0, bf16x4);
    bf16x4 h1 = __builtin_convertvector(v1, bf16x4);
    f32x4 r0 = v0 - __builtin_convertvector(h0, f32x4);
    f32x4 r1 = v1 - __builtin_convertvector(h1, f32x4);
    bf16x4 l0 = __builtin_convertvector(r0, bf16x4);
    bf16x4 l1 = __builtin_convertvector(r1, bf16x4);
    s16x4 h0s = __builtin_bit_cast(s16x4, h0), h1s = __builtin_bit_cast(s16x4, h1);
    s16x4 l0s = __builtin_bit_cast(s16x4, l0), l1s = __builtin_bit_cast(s16x4, l1);
    *hi = __builtin_shufflevector(h0s, h1s, 0, 1, 2, 3, 4, 5, 6, 7);
    *lo = __builtin_shufflevector(l0s, l1s, 0, 1, 2, 3, 4, 5, 6, 7);
}

__device__ __forceinline__ s16x8 pack_bf16(f32x4 v0, f32x4 v1) {
    bf16x4 h0 = __builtin_convertvector(v0, bf16x4);
    bf16x4 h1 = __builtin_convertvector(v1, bf16x4);
    s16x4 a = __builtin_bit_cast(s16x4, h0), b = __builtin_bit_cast(s16x4, h1);
    return __builtin_shufflevector(a, b, 0, 1, 2, 3, 4, 5, 6, 7);
}

// async global->LDS, 16 B per lane; lds dest must be wave-uniform (HW adds lane*16)
__device__ __forceinline__ void glds16(const void* g, void* l) {
    __builtin_amdgcn_global_load_lds(
        (const __attribute__((address_space(1))) unsigned int*)g,
        (__attribute__((address_space(3))) unsigned int*)l,
        16, 0, 0);
}

// ---------------- prep: wt_build (blocks 0-47) + ssq zero (48-191) + mask detect (192) ----
__global__ __launch_bounds__(256) void prep_k(
    const float* __restrict__ W, unsigned short* __restrict__ wthi,
    const unsigned int* __restrict__ pmask_w, unsigned int* __restrict__ ctrl,
    float* __restrict__ ssq) {
    __shared__ unsigned int rr[256];
    int b = blockIdx.x, t = threadIdx.x;
    if (b < 48) {
        int tid = b * 256 + t;
        int nt = tid / (24 * 64);
        int r = tid - nt * 24 * 64;
        int ks = r / 64, lane = r - ks * 64;
        int m = lane & 15, quad = lane >> 4;
        unsigned short* o = wthi + (size_t)tid * 8;
#pragma unroll
        for (int j = 0; j < 8; j++) {
            int k = ks * 32 + quad * 8 + j;
            o[j] = f2bf(W[(size_t)k * D_ + nt * 16 + m]);
        }
    } else if (b < 192) {
        ssq[(b - 48) * 256 + t] = 0.f;       // 144*256 = 36864 exactly
    } else {
        unsigned int f1 = 0, f3 = 0, f4 = 0;
        for (int w = t; w < 4320; w += 256) {
            unsigned int v = pmask_w[w];
            f1 |= v & 0x0000ff00u;                 // byte %4==1 -> 1-byte layout
            f3 |= v & 0xff000000u;                 // byte %4==3 -> float32
            if (w & 1) f4 |= v & 0x000000ffu;      // byte %8==4 -> int32
        }
        rr[t] = f1; __syncthreads();
        for (int s2 = 128; s2; s2 >>= 1) { if (t < s2) rr[t] |= rr[t + s2]; __syncthreads(); }
        if (!t) ctrl[0] = rr[0];
        __syncthreads();
        rr[t] = f3; __syncthreads();
        for (int s2 = 128; s2; s2 >>= 1) { if (t < s2) rr[t] |= rr[t + s2]; __syncthreads(); }
        if (!t) ctrl[1] = rr[0];
        __syncthreads();
        rr[t] = f4; __syncthreads();
        for (int s2 = 128; s2; s2 >>= 1) { if (t < s2) rr[t] |= rr[t + s2]; __syncthreads(); }
        if (!t) ctrl[2] = rr[0];
    }
}

// ---------------- proj: block = 32-row group, 4 waves = K-quarters, 2 m-subtiles/wave ----
// Each bh[8] B-fragment group feeds 32 MFMAs (2 m-subtiles) -> B L2 traffic halved vs
// 16-row waves. acc[2][8] (64 VGPR). LDS combine in two 16-row rounds (32 KB buffer).
// Epilogue fuses sequence-axis sum-of-squares (atomicAdd ssq).
__global__ __launch_bounds__(256) void proj_k(
    const float* __restrict__ qh, const float* __restrict__ ph, const float* __restrict__ nh,
    const unsigned short* __restrict__ wthi, const float* __restrict__ bias,
    float* __restrict__ x, float* __restrict__ ssq,
    const void* __restrict__ pm, const void* __restrict__ nm,
    const unsigned int* __restrict__ ctrl, unsigned char* __restrict__ maskc) {
    __shared__ f32x4 part[4][8][64];                 // 32 KB
    int b = blockIdx.x;
    if (b >= 1185) {                                 // ---- mask canon: 135 blocks exact ----
        int i = (b - 1185) * 256 + threadIdx.x;      // < 34560
        const void* src = (i < B_ * LP) ? pm : nm;
        int j = (i < B_ * LP) ? i : i - B_ * LP;
        unsigned int c1 = ctrl[0], c3 = ctrl[1], c4 = ctrl[2];
        bool bit;
        if (c1 > 0)       bit = ((const unsigned char*)src)[j] != 0;
        else if (c3 > 0)  bit = ((const float*)src)[j] != 0.0f;
        else if (c4 > 0)  bit = ((const int*)src)[j] != 0;
        else              bit = ((const long long*)src)[j] != 0;
        maskc[i] = bit ? 1 : 0;
        return;
    }
    int wave = threadIdx.x >> 6, lane = threadIdx.x & 63;
    const float* src; int row0l; int growbase;
    if (b < 105)      { src = qh; row0l = b * 32;         growbase = row0l; }
    else if (b < 645) { src = ph; row0l = (b - 105) * 32; growbase = QROWS + row0l; }
    else              { src = nh; row0l = (b - 645) * 32; growbase = QROWS + PROWS + row0l; }
    int m = lane & 15, quad = lane >> 4;
    const float* ap0 = src + (size_t)(row0l + m) * H_ + wave * 192 + quad * 8;
    const float* ap1 = ap0 + (size_t)16 * H_;

    f32x4 acc[2][8];
#pragma unroll
    for (int mt = 0; mt < 2; mt++)
#pragma unroll
        for (int nt = 0; nt < 8; nt++) acc[mt][nt] = (f32x4){0.f, 0.f, 0.f, 0.f};

#pragma unroll
    for (int kl = 0; kl < 6; kl++) {
        f32x4 u0 = *(const f32x4*)(ap0 + kl * 32);
        f32x4 u1 = *(const f32x4*)(ap0 + kl * 32 + 4);
        f32x4 w0 = *(const f32x4*)(ap1 + kl * 32);
        f32x4 w1 = *(const f32x4*)(ap1 + kl * 32 + 4);
        s16x8 a0hi, a0lo, a1hi, a1lo;
        cvt_hilo(u0, u1, &a0hi, &a0lo);
        cvt_hilo(w0, w1, &a1hi, &a1lo);
        int ksg = wave * 6 + kl;
        s16x8 bh[8];
#pragma unroll
        for (int nt = 0; nt < 8; nt++)
            bh[nt] = *(const s16x8*)(wthi + ((size_t)(nt * 24 + ksg) * 64 + lane) * 8);
#pragma unroll
        for (int nt = 0; nt < 8; nt++) {
            acc[0][nt] = __builtin_amdgcn_mfma_f32_16x16x32_bf16(a0hi, bh[nt], acc[0][nt], 0, 0, 0);
            acc[0][nt] = __builtin_amdgcn_mfma_f32_16x16x32_bf16(a0lo, bh[nt], acc[0][nt], 0, 0, 0);
            acc[1][nt] = __builtin_amdgcn_mfma_f32_16x16x32_bf16(a1hi, bh[nt], acc[1][nt], 0, 0, 0);
            acc[1][nt] = __builtin_amdgcn_mfma_f32_16x16x32_bf16(a1lo, bh[nt], acc[1][nt], 0, 0, 0);
        }
    }

    // combine K-partials + write x + fused ssq, one 16-row round per mt
#pragma unroll
    for (int mt = 0; mt < 2; mt++) {
        if (mt) __syncthreads();                     // previous round's reads complete
#pragma unroll
        for (int nt = 0; nt < 8; nt++) part[wave][nt][lane] = acc[mt][nt];
        __syncthreads();

        int base = growbase + mt * 16;
        int bk0, bk1, b1start;
        if (base < QROWS)              { bk0 = base / 35;  bk1 = (base + 15) / 35;
                                         b1start = bk1 * 35; }
        else if (base < QROWS + PROWS) { int r0 = base - QROWS;
                                         bk0 = 96 + r0 / 180;  bk1 = 96 + (r0 + 15) / 180;
                                         b1start = QROWS + (bk1 - 96) * 180; }
        else                           { int r0 = base - QROWS - PROWS;
                                         bk0 = 192 + r0 / 180; bk1 = 192 + (r0 + 15) / 180;
                                         b1start = QROWS + PROWS + (bk1 - 192) * 180; }

#pragma unroll
        for (int q2 = 0; q2 < 2; q2++) {
            int nt = wave * 2 + q2;
            f32x4 s = part[0][nt][lane];
            s += part[1][nt][lane];
            s += part[2][nt][lane];
            s += part[3][nt][lane];
            int col = nt * 16 + m;
            float bv = bias[col];
            float slo = 0.f, shi = 0.f;
#pragma unroll
            for (int r = 0; r < 4; r++) {
                int grow = base + quad * 4 + r;
                float v = s[r] + bv;
                x[(size_t)grow * D_ + col] = v;
                float v2 = v * v;
                if (bk1 > bk0 && grow >= b1start) shi += v2; else slo += v2;
            }
            slo += __shfl_xor(slo, 16); slo += __shfl_xor(slo, 32);
            if (quad == 0) atomicAdd(ssq + (size_t)bk0 * D_ + col, slo);
            if (bk1 > bk0) {
                shi += __shfl_xor(shi, 16); shi += __shfl_xor(shi, 32);
                if (quad == 0) atomicAdd(ssq + (size_t)bk1 * D_ + col, shi);
            }
        }
    }
}

// ---------------- scale + bf16 + scatter: one thread per 16B frag chunk -----------------
__global__ __launch_bounds__(256) void scatter_k(
    const float* __restrict__ x, const float* __restrict__ ssq,
    const unsigned char* __restrict__ maskc,
    unsigned short* __restrict__ qfrag, unsigned short* __restrict__ pfrag) {
    int c = blockIdx.x * 256 + threadIdx.x;          // 651264 total = 2544*256
    int lane = c & 63, ks = (c >> 6) & 3;
    int quad = lane >> 4, mm = lane & 15;
    int d0 = ks * 32 + quad * 8;
    if (c < 61440) {
        int g = c >> 8;                              // qp*5 + mt
        int mt = g % 5, qp = g / 5;
        int prow = mt * 16 + mm;
        s16x8 outv = (s16x8){0, 0, 0, 0, 0, 0, 0, 0};
        if (prow < 70) {
            int hi = prow >= 35;
            int bq = qp * 2 + hi;
            int l = prow - hi * 35;
            size_t row = (size_t)bq * 35 + l;
            const f32x4* px = (const f32x4*)(x + row * D_ + d0);
            f32x4 v0 = px[0], v1 = px[1];
            const f32x4* pq = (const f32x4*)(ssq + (size_t)bq * D_ + d0);
            f32x4 q0 = pq[0], q1 = pq[1];
            f32x4 r0, r1;
#pragma unroll
            for (int j = 0; j < 4; j++) {
                r0[j] = rsqrtf(fmaxf(q0[j], 1e-24f));
                r1[j] = rsqrtf(fmaxf(q1[j], 1e-24f));
            }
            outv = pack_bf16(v0 * r0, v1 * r1);
        }
        *(s16x8*)(qfrag + (size_t)c * 8) = outv;
    } else {
        int c2 = c - 61440;
        int g = c2 >> 8;                             // pbk*12 + nt
        int nt = g % 12, pbk = g / 12;
        int l = nt * 16 + mm;
        int lsrc = (l < LP && maskc[pbk * LP + l]) ? l : 0;
        size_t row = QROWS + (size_t)pbk * LP + lsrc;
        const f32x4* px = (const f32x4*)(x + row * D_ + d0);
        f32x4 v0 = px[0], v1 = px[1];
        const f32x4* pq = (const f32x4*)(ssq + (size_t)(96 + pbk) * D_ + d0);
        f32x4 q0 = pq[0], q1 = pq[1];
        f32x4 r0, r1;
#pragma unroll
        for (int j = 0; j < 4; j++) {
            r0[j] = rsqrtf(fmaxf(q0[j], 1e-24f));
            r1[j] = rsqrtf(fmaxf(q1[j], 1e-24f));
        }
        *(s16x8*)(pfrag + (size_t)c2 * 8) = pack_bf16(v0 * r0, v1 * r1);
    }
}

// ---------------- late interaction: p-block staged via glds, XCD-pinned, mask-free ------
__global__ __launch_bounds__(256, 3) void interact_k(
    const unsigned short* __restrict__ qfrag, const unsigned short* __restrict__ pfrag,
    float* __restrict__ out) {
    __shared__ unsigned short plds[24576];           // 48 KB, shared by all 4 waves
    int wave = threadIdx.x >> 6, lane = threadIdx.x & 63;
    int b = blockIdx.x;                              // 2304 blocks
    int xcd = b & 7, i = b >> 3;                     // i in [0,288)
    int c = xcd * 24 + (i % 24);                     // [0,192)
    int qg = i / 24;                                 // [0,12)
    int side = c / 96, pb = c - side * 96;
    int qp = qg * 4 + wave;
    int m = lane & 15, quad = lane >> 4;

    const unsigned short* pbase = pfrag + (size_t)c * 24576;
    const unsigned short* qbase = qfrag + (size_t)qp * 10240;

    // wave stages its 3 nt-groups: 12 x 1 KB async
#pragma unroll
    for (int ntl = 0; ntl < 3; ntl++) {
        int nt = wave * 3 + ntl;
#pragma unroll
        for (int ks = 0; ks < 4; ks++)
            glds16(pbase + ((size_t)(nt * 4 + ks) * 64 + lane) * 8,
                   &plds[(size_t)(nt * 4 + ks) * 512]);
    }

    s16x8 a[5][4];
#pragma unroll
    for (int mt = 0; mt < 5; mt++)
#pragma unroll
        for (int ks = 0; ks < 4; ks++)
            a[mt][ks] = *(const s16x8*)(qbase + ((size_t)(mt * 4 + ks) * 64 + lane) * 8);

    __syncthreads();                                 // drain staging

    const f32x4 zero4 = (f32x4){0.f, 0.f, 0.f, 0.f};
    float rmax[5][4];
#pragma unroll
    for (int mt = 0; mt < 5; mt++)
#pragma unroll
        for (int rr = 0; rr < 4; rr++) rmax[mt][rr] = NEGF;

    for (int nt = 0; nt < 12; nt++) {
        s16x8 bfr[4];
#pragma unroll
        for (int ks = 0; ks < 4; ks++)
            bfr[ks] = *(const s16x8*)&plds[((size_t)(nt * 4 + ks) * 64 + lane) * 8];
#pragma unroll
        for (int mt = 0; mt < 5; mt++) {
            f32x4 acc = __builtin_amdgcn_mfma_f32_16x16x32_bf16(a[mt][0], bfr[0], zero4, 0, 0, 0);
            acc = __builtin_amdgcn_mfma_f32_16x16x32_bf16(a[mt][1], bfr[1], acc, 0, 0, 0);
            acc = __builtin_amdgcn_mfma_f32_16x16x32_bf16(a[mt][2], bfr[2], acc, 0, 0, 0);
            acc = __builtin_amdgcn_mfma_f32_16x16x32_bf16(a[mt][3], bfr[3], acc, 0, 0, 0);
#pragma unroll
            for (int rr = 0; rr < 4; rr++)
                rmax[mt][rr] = fmaxf(rmax[mt][rr], acc[rr]);
        }
    }

#pragma unroll
    for (int mt = 0; mt < 5; mt++)
#pragma unroll
        for (int rr = 0; rr < 4; rr++) {
            float v = rmax[mt][rr];
            v = fmaxf(v, __shfl_xor(v, 1));
            v = fmaxf(v, __shfl_xor(v, 2));
            v = fmaxf(v, __shfl_xor(v, 4));
            v = fmaxf(v, __shfl_xor(v, 8));
            rmax[mt][rr] = v;
        }
    float s0 = 0.f, s1 = 0.f;
#pragma unroll
    for (int mt = 0; mt < 5; mt++)
#pragma unroll
        for (int rr = 0; rr < 4; rr++) {
            int prow = mt * 16 + quad * 4 + rr;
            float v = rmax[mt][rr];
            if (prow < 35) s0 += v;
            else if (prow < 70) s1 += v;
        }
    s0 += __shfl_xor(s0, 16); s0 += __shfl_xor(s0, 32);
    s1 += __shfl_xor(s1, 16); s1 += __shfl_xor(s1, 32);
    if (lane == 0) {
        int qb0 = qp * 2, qb1 = qp * 2 + 1;
        out[(size_t)qb0 * (2 * B_) + side * B_ + pb] = s0;
        out[(size_t)qb1 * (2 * B_) + side * B_ + pb] = s1;
    }
}

// ---------------- launch ----------------
extern "C" void kernel_launch(void* const* d_in, const int* in_sizes, int n_in,
                              void* d_out, int out_size, void* d_ws, size_t ws_size,
                              hipStream_t stream) {
    const float* qh   = (const float*)d_in[0];
    const float* ph   = (const float*)d_in[1];
    const float* nh   = (const float*)d_in[2];
    const float* W    = (const float*)d_in[3];
    const float* bias = (const float*)d_in[4];
    const void* pmask = d_in[5];
    const void* nmask = d_in[6];
    float* out = (float*)d_out;
    char* ws = (char*)d_ws;

    constexpr size_t CTRL_OFF  = 0;                          // 256 B
    constexpr size_t WTHI_OFF  = 256;                        // 196608 B
    constexpr size_t MASKC_OFF = WTHI_OFF + 196608;          // 34560 B -> ends 231424
    constexpr size_t SSQ_OFF   = 231424;                     // 147456 B
    constexpr size_t X_OFF     = SSQ_OFF + 147456;           // 19415040 B
    constexpr size_t QFRAG_OFF = X_OFF + (size_t)NROWS * D_ * 4;   // 983040 B
    constexpr size_t PFRAG_OFF = QFRAG_OFF + 983040;         // 9437184 B

    unsigned int* ctrl     = (unsigned int*)(ws + CTRL_OFF);
    unsigned short* wthi   = (unsigned short*)(ws + WTHI_OFF);
    unsigned char* maskc   = (unsigned char*)(ws + MASKC_OFF);
    float* ssq             = (float*)(ws + SSQ_OFF);
    float* x               = (float*)(ws + X_OFF);
    unsigned short* qfrag  = (unsigned short*)(ws + QFRAG_OFF);
    unsigned short* pfrag  = (unsigned short*)(ws + PFRAG_OFF);

    prep_k<<<193, 256, 0, stream>>>(W, wthi, (const unsigned int*)pmask, ctrl, ssq);
    proj_k<<<1185 + 135, 256, 0, stream>>>(qh, ph, nh, wthi, bias, x, ssq,
                                           pmask, nmask, ctrl, maskc);
    scatter_k<<<2544, 256, 0, stream>>>(x, ssq, maskc, qfrag, pfrag);
    interact_k<<<2304, 256, 0, stream>>>(qfrag, pfrag, out);
}

// Round 9
// 202.455 us; speedup vs baseline: 1.0865x; 1.0447x over previous
//
#include <hip/hip_runtime.h>

typedef __attribute__((ext_vector_type(4))) float f32x4;
typedef __attribute__((ext_vector_type(8))) short s16x8;
typedef __attribute__((ext_vector_type(4))) short s16x4;
typedef __bf16 bf16x4 __attribute__((ext_vector_type(4)));

#define B_   96
#define NQ   35
#define LP   180
#define H_   768
#define D_   128
#define NEGF (-1e30f)

#define NROWS 37920
#define QROWS 3360
#define PROWS 17280

__device__ __forceinline__ unsigned short f2bf(float f) {
    return __builtin_bit_cast(unsigned short, (__bf16)f);
}

__device__ __forceinline__ void cvt_hilo(f32x4 v0, f32x4 v1, s16x8* hi, s16x8* lo) {
    bf16x4 h0 = __builtin_convertvector(v0, bf16x4);
    bf16x4 h1 = __builtin_convertvector(v1, bf16x4);
    f32x4 r0 = v0 - __builtin_convertvector(h0, f32x4);
    f32x4 r1 = v1 - __builtin_convertvector(h1, f32x4);
    bf16x4 l0 = __builtin_convertvector(r0, bf16x4);
    bf16x4 l1 = __builtin_convertvector(r1, bf16x4);
    s16x4 h0s = __builtin_bit_cast(s16x4, h0), h1s = __builtin_bit_cast(s16x4, h1);
    s16x4 l0s = __builtin_bit_cast(s16x4, l0), l1s = __builtin_bit_cast(s16x4, l1);
    *hi = __builtin_shufflevector(h0s, h1s, 0, 1, 2, 3, 4, 5, 6, 7);
    *lo = __builtin_shufflevector(l0s, l1s, 0, 1, 2, 3, 4, 5, 6, 7);
}

__device__ __forceinline__ s16x8 pack_bf16(f32x4 v0, f32x4 v1) {
    bf16x4 h0 = __builtin_convertvector(v0, bf16x4);
    bf16x4 h1 = __builtin_convertvector(v1, bf16x4);
    s16x4 a = __builtin_bit_cast(s16x4, h0), b = __builtin_bit_cast(s16x4, h1);
    return __builtin_shufflevector(a, b, 0, 1, 2, 3, 4, 5, 6, 7);
}

// async global->LDS, 16 B per lane; lds dest must be wave-uniform (HW adds lane*16)
__device__ __forceinline__ void glds16(const void* g, void* l) {
    __builtin_amdgcn_global_load_lds(
        (const __attribute__((address_space(1))) unsigned int*)g,
        (__attribute__((address_space(3))) unsigned int*)l,
        16, 0, 0);
}

// ---------------- prep: wt_build (blocks 0-47) + ssq zero (48-191) + mask detect (192) ----
__global__ __launch_bounds__(256) void prep_k(
    const float* __restrict__ W, unsigned short* __restrict__ wthi,
    const unsigned int* __restrict__ pmask_w, unsigned int* __restrict__ ctrl,
    float* __restrict__ ssq) {
    __shared__ unsigned int rr[256];
    int b = blockIdx.x, t = threadIdx.x;
    if (b < 48) {
        int tid = b * 256 + t;
        int nt = tid / (24 * 64);
        int r = tid - nt * 24 * 64;
        int ks = r / 64, lane = r - ks * 64;
        int m = lane & 15, quad = lane >> 4;
        unsigned short* o = wthi + (size_t)tid * 8;
#pragma unroll
        for (int j = 0; j < 8; j++) {
            int k = ks * 32 + quad * 8 + j;
            o[j] = f2bf(W[(size_t)k * D_ + nt * 16 + m]);
        }
    } else if (b < 192) {
        ssq[(b - 48) * 256 + t] = 0.f;       // 144*256 = 36864 exactly
    } else {
        unsigned int f1 = 0, f3 = 0, f4 = 0;
        for (int w = t; w < 4320; w += 256) {
            unsigned int v = pmask_w[w];
            f1 |= v & 0x0000ff00u;                 // byte %4==1 -> 1-byte layout
            f3 |= v & 0xff000000u;                 // byte %4==3 -> float32
            if (w & 1) f4 |= v & 0x000000ffu;      // byte %8==4 -> int32
        }
        rr[t] = f1; __syncthreads();
        for (int s2 = 128; s2; s2 >>= 1) { if (t < s2) rr[t] |= rr[t + s2]; __syncthreads(); }
        if (!t) ctrl[0] = rr[0];
        __syncthreads();
        rr[t] = f3; __syncthreads();
        for (int s2 = 128; s2; s2 >>= 1) { if (t < s2) rr[t] |= rr[t + s2]; __syncthreads(); }
        if (!t) ctrl[1] = rr[0];
        __syncthreads();
        rr[t] = f4; __syncthreads();
        for (int s2 = 128; s2; s2 >>= 1) { if (t < s2) rr[t] |= rr[t + s2]; __syncthreads(); }
        if (!t) ctrl[2] = rr[0];
    }
}

// ---------------- proj v2: dense-stream A through LDS transpose, double-buffered --------
// Block = 32 rows x 128 cols x full K. Per step (BK=64): 8 KB A-slab loaded DENSE
// (thread t -> row t/16, 16 contiguous bytes), stored to fragment-ordered LDS slots,
// one barrier, MFMA from lane-contiguous (conflict-free) LDS reads. 12 steps,
// prefetch depth 1. Waves partition the 8 nt column-tiles (2 each) -> exclusive
// (row,col) output tiles; epilogue fuses x write + sequence-axis ssq atomics.
__global__ __launch_bounds__(256) void proj_k(
    const float* __restrict__ qh, const float* __restrict__ ph, const float* __restrict__ nh,
    const unsigned short* __restrict__ wthi, const float* __restrict__ bias,
    float* __restrict__ x, float* __restrict__ ssq,
    const void* __restrict__ pm, const void* __restrict__ nm,
    const unsigned int* __restrict__ ctrl, unsigned char* __restrict__ maskc) {
    __shared__ f32x4 abuf[2][8][64];                 // 16 KB: [buf][ksg*4+mt*2+half][lane]
    int b = blockIdx.x;
    if (b >= 1185) {                                 // ---- mask canon: 135 blocks exact ----
        int i = (b - 1185) * 256 + threadIdx.x;      // < 34560
        const void* src = (i < B_ * LP) ? pm : nm;
        int j = (i < B_ * LP) ? i : i - B_ * LP;
        unsigned int c1 = ctrl[0], c3 = ctrl[1], c4 = ctrl[2];
        bool bit;
        if (c1 > 0)       bit = ((const unsigned char*)src)[j] != 0;
        else if (c3 > 0)  bit = ((const float*)src)[j] != 0.0f;
        else if (c4 > 0)  bit = ((const int*)src)[j] != 0;
        else              bit = ((const long long*)src)[j] != 0;
        maskc[i] = bit ? 1 : 0;
        return;
    }
    int t = threadIdx.x;
    int wave = t >> 6, lane = t & 63;
    const float* src; int row0l; int growbase;
    if (b < 105)      { src = qh; row0l = b * 32;         growbase = row0l; }
    else if (b < 645) { src = ph; row0l = (b - 105) * 32; growbase = QROWS + row0l; }
    else              { src = nh; row0l = (b - 645) * 32; growbase = QROWS + PROWS + row0l; }
    int m = lane & 15, quad = lane >> 4;

    // staging roles: thread t handles rows (t>>4) and 16+(t>>4), 16 B column chunk c=t&15
    int srow = t >> 4, c = t & 15;
    int sksg = c >> 3, kk = c & 7, sq = kk >> 1, shalf = kk & 1;
    int slane = srow + (sq << 4);
    int slot0 = sksg * 4 + shalf;                    // mt = 0
    int slot1 = sksg * 4 + 2 + shalf;                // mt = 1
    const float* gp0 = src + ((size_t)(row0l + srow)) * H_ + c * 4;
    const float* gp1 = gp0 + (size_t)16 * H_;

    f32x4 acc[2][2];
#pragma unroll
    for (int mt = 0; mt < 2; mt++)
#pragma unroll
        for (int ntl = 0; ntl < 2; ntl++) acc[mt][ntl] = (f32x4){0.f, 0.f, 0.f, 0.f};

    int nt0 = wave * 2, nt1 = wave * 2 + 1;

    // prologue: prefetch step 0
    f32x4 pv0 = *(const f32x4*)gp0;
    f32x4 pv1 = *(const f32x4*)gp1;

#pragma unroll 2
    for (int s = 0; s < 12; s++) {
        abuf[s & 1][slot0][slane] = pv0;
        abuf[s & 1][slot1][slane] = pv1;
        __syncthreads();
        if (s < 11) {
            pv0 = *(const f32x4*)(gp0 + (s + 1) * 64);
            pv1 = *(const f32x4*)(gp1 + (s + 1) * 64);
        }
#pragma unroll
        for (int ksg = 0; ksg < 2; ksg++) {
            int ksgg = s * 2 + ksg;
            s16x8 ahi[2], alo[2];
#pragma unroll
            for (int mt = 0; mt < 2; mt++) {
                f32x4 v0 = abuf[s & 1][ksg * 4 + mt * 2 + 0][lane];
                f32x4 v1 = abuf[s & 1][ksg * 4 + mt * 2 + 1][lane];
                cvt_hilo(v0, v1, &ahi[mt], &alo[mt]);
            }
            s16x8 bh0 = *(const s16x8*)(wthi + ((size_t)(nt0 * 24 + ksgg) * 64 + lane) * 8);
            s16x8 bh1 = *(const s16x8*)(wthi + ((size_t)(nt1 * 24 + ksgg) * 64 + lane) * 8);
#pragma unroll
            for (int mt = 0; mt < 2; mt++) {
                acc[mt][0] = __builtin_amdgcn_mfma_f32_16x16x32_bf16(ahi[mt], bh0, acc[mt][0], 0, 0, 0);
                acc[mt][0] = __builtin_amdgcn_mfma_f32_16x16x32_bf16(alo[mt], bh0, acc[mt][0], 0, 0, 0);
                acc[mt][1] = __builtin_amdgcn_mfma_f32_16x16x32_bf16(ahi[mt], bh1, acc[mt][1], 0, 0, 0);
                acc[mt][1] = __builtin_amdgcn_mfma_f32_16x16x32_bf16(alo[mt], bh1, acc[mt][1], 0, 0, 0);
            }
        }
    }

    // epilogue: x write + fused ssq (wave owns cols [wave*32, wave*32+32), all 32 rows)
#pragma unroll
    for (int mt = 0; mt < 2; mt++) {
        int base = growbase + mt * 16;
        int bk0, bk1, b1start;
        if (base < QROWS)              { bk0 = base / 35;  bk1 = (base + 15) / 35;
                                         b1start = bk1 * 35; }
        else if (base < QROWS + PROWS) { int r0 = base - QROWS;
                                         bk0 = 96 + r0 / 180;  bk1 = 96 + (r0 + 15) / 180;
                                         b1start = QROWS + (bk1 - 96) * 180; }
        else                           { int r0 = base - QROWS - PROWS;
                                         bk0 = 192 + r0 / 180; bk1 = 192 + (r0 + 15) / 180;
                                         b1start = QROWS + PROWS + (bk1 - 192) * 180; }
#pragma unroll
        for (int ntl = 0; ntl < 2; ntl++) {
            int col = (wave * 2 + ntl) * 16 + m;
            float bv = bias[col];
            f32x4 s4 = acc[mt][ntl];
            float slo = 0.f, shi = 0.f;
#pragma unroll
            for (int r = 0; r < 4; r++) {
                int grow = base + quad * 4 + r;
                float v = s4[r] + bv;
                x[(size_t)grow * D_ + col] = v;
                float v2 = v * v;
                if (bk1 > bk0 && grow >= b1start) shi += v2; else slo += v2;
            }
            slo += __shfl_xor(slo, 16); slo += __shfl_xor(slo, 32);
            if (quad == 0) atomicAdd(ssq + (size_t)bk0 * D_ + col, slo);
            if (bk1 > bk0) {
                shi += __shfl_xor(shi, 16); shi += __shfl_xor(shi, 32);
                if (quad == 0) atomicAdd(ssq + (size_t)bk1 * D_ + col, shi);
            }
        }
    }
}

// ---------------- scale + bf16 + scatter: one thread per 16B frag chunk -----------------
__global__ __launch_bounds__(256) void scatter_k(
    const float* __restrict__ x, const float* __restrict__ ssq,
    const unsigned char* __restrict__ maskc,
    unsigned short* __restrict__ qfrag, unsigned short* __restrict__ pfrag) {
    int c = blockIdx.x * 256 + threadIdx.x;          // 651264 total = 2544*256
    int lane = c & 63, ks = (c >> 6) & 3;
    int quad = lane >> 4, mm = lane & 15;
    int d0 = ks * 32 + quad * 8;
    if (c < 61440) {
        int g = c >> 8;                              // qp*5 + mt
        int mt = g % 5, qp = g / 5;
        int prow = mt * 16 + mm;
        s16x8 outv = (s16x8){0, 0, 0, 0, 0, 0, 0, 0};
        if (prow < 70) {
            int hi = prow >= 35;
            int bq = qp * 2 + hi;
            int l = prow - hi * 35;
            size_t row = (size_t)bq * 35 + l;
            const f32x4* px = (const f32x4*)(x + row * D_ + d0);
            f32x4 v0 = px[0], v1 = px[1];
            const f32x4* pq = (const f32x4*)(ssq + (size_t)bq * D_ + d0);
            f32x4 q0 = pq[0], q1 = pq[1];
            f32x4 r0, r1;
#pragma unroll
            for (int j = 0; j < 4; j++) {
                r0[j] = rsqrtf(fmaxf(q0[j], 1e-24f));
                r1[j] = rsqrtf(fmaxf(q1[j], 1e-24f));
            }
            outv = pack_bf16(v0 * r0, v1 * r1);
        }
        *(s16x8*)(qfrag + (size_t)c * 8) = outv;
    } else {
        int c2 = c - 61440;
        int g = c2 >> 8;                             // pbk*12 + nt
        int nt = g % 12, pbk = g / 12;
        int l = nt * 16 + mm;
        int lsrc = (l < LP && maskc[pbk * LP + l]) ? l : 0;
        size_t row = QROWS + (size_t)pbk * LP + lsrc;
        const f32x4* px = (const f32x4*)(x + row * D_ + d0);
        f32x4 v0 = px[0], v1 = px[1];
        const f32x4* pq = (const f32x4*)(ssq + (size_t)(96 + pbk) * D_ + d0);
        f32x4 q0 = pq[0], q1 = pq[1];
        f32x4 r0, r1;
#pragma unroll
        for (int j = 0; j < 4; j++) {
            r0[j] = rsqrtf(fmaxf(q0[j], 1e-24f));
            r1[j] = rsqrtf(fmaxf(q1[j], 1e-24f));
        }
        *(s16x8*)(pfrag + (size_t)c2 * 8) = pack_bf16(v0 * r0, v1 * r1);
    }
}

// ---------------- late interaction: p-block staged via glds, XCD-pinned, mask-free ------
__global__ __launch_bounds__(256, 3) void interact_k(
    const unsigned short* __restrict__ qfrag, const unsigned short* __restrict__ pfrag,
    float* __restrict__ out) {
    __shared__ unsigned short plds[24576];           // 48 KB, shared by all 4 waves
    int wave = threadIdx.x >> 6, lane = threadIdx.x & 63;
    int b = blockIdx.x;                              // 2304 blocks
    int xcd = b & 7, i = b >> 3;                     // i in [0,288)
    int c = xcd * 24 + (i % 24);                     // [0,192)
    int qg = i / 24;                                 // [0,12)
    int side = c / 96, pb = c - side * 96;
    int qp = qg * 4 + wave;
    int m = lane & 15, quad = lane >> 4;

    const unsigned short* pbase = pfrag + (size_t)c * 24576;
    const unsigned short* qbase = qfrag + (size_t)qp * 10240;

#pragma unroll
    for (int ntl = 0; ntl < 3; ntl++) {
        int nt = wave * 3 + ntl;
#pragma unroll
        for (int ks = 0; ks < 4; ks++)
            glds16(pbase + ((size_t)(nt * 4 + ks) * 64 + lane) * 8,
                   &plds[(size_t)(nt * 4 + ks) * 512]);
    }

    s16x8 a[5][4];
#pragma unroll
    for (int mt = 0; mt < 5; mt++)
#pragma unroll
        for (int ks = 0; ks < 4; ks++)
            a[mt][ks] = *(const s16x8*)(qbase + ((size_t)(mt * 4 + ks) * 64 + lane) * 8);

    __syncthreads();                                 // drain staging

    const f32x4 zero4 = (f32x4){0.f, 0.f, 0.f, 0.f};
    float rmax[5][4];
#pragma unroll
    for (int mt = 0; mt < 5; mt++)
#pragma unroll
        for (int rr = 0; rr < 4; rr++) rmax[mt][rr] = NEGF;

    for (int nt = 0; nt < 12; nt++) {
        s16x8 bfr[4];
#pragma unroll
        for (int ks = 0; ks < 4; ks++)
            bfr[ks] = *(const s16x8*)&plds[((size_t)(nt * 4 + ks) * 64 + lane) * 8];
#pragma unroll
        for (int mt = 0; mt < 5; mt++) {
            f32x4 acc = __builtin_amdgcn_mfma_f32_16x16x32_bf16(a[mt][0], bfr[0], zero4, 0, 0, 0);
            acc = __builtin_amdgcn_mfma_f32_16x16x32_bf16(a[mt][1], bfr[1], acc, 0, 0, 0);
            acc = __builtin_amdgcn_mfma_f32_16x16x32_bf16(a[mt][2], bfr[2], acc, 0, 0, 0);
            acc = __builtin_amdgcn_mfma_f32_16x16x32_bf16(a[mt][3], bfr[3], acc, 0, 0, 0);
#pragma unroll
            for (int rr = 0; rr < 4; rr++)
                rmax[mt][rr] = fmaxf(rmax[mt][rr], acc[rr]);
        }
    }

#pragma unroll
    for (int mt = 0; mt < 5; mt++)
#pragma unroll
        for (int rr = 0; rr < 4; rr++) {
            float v = rmax[mt][rr];
            v = fmaxf(v, __shfl_xor(v, 1));
            v = fmaxf(v, __shfl_xor(v, 2));
            v = fmaxf(v, __shfl_xor(v, 4));
            v = fmaxf(v, __shfl_xor(v, 8));
            rmax[mt][rr] = v;
        }
    float s0 = 0.f, s1 = 0.f;
#pragma unroll
    for (int mt = 0; mt < 5; mt++)
#pragma unroll
        for (int rr = 0; rr < 4; rr++) {
            int prow = mt * 16 + quad * 4 + rr;
            float v = rmax[mt][rr];
            if (prow < 35) s0 += v;
            else if (prow < 70) s1 += v;
        }
    s0 += __shfl_xor(s0, 16); s0 += __shfl_xor(s0, 32);
    s1 += __shfl_xor(s1, 16); s1 += __shfl_xor(s1, 32);
    if (lane == 0) {
        int qb0 = qp * 2, qb1 = qp * 2 + 1;
        out[(size_t)qb0 * (2 * B_) + side * B_ + pb] = s0;
        out[(size_t)qb1 * (2 * B_) + side * B_ + pb] = s1;
    }
}

// ---------------- launch ----------------
extern "C" void kernel_launch(void* const* d_in, const int* in_sizes, int n_in,
                              void* d_out, int out_size, void* d_ws, size_t ws_size,
                              hipStream_t stream) {
    const float* qh   = (const float*)d_in[0];
    const float* ph   = (const float*)d_in[1];
    const float* nh   = (const float*)d_in[2];
    const float* W    = (const float*)d_in[3];
    const float* bias = (const float*)d_in[4];
    const void* pmask = d_in[5];
    const void* nmask = d_in[6];
    float* out = (float*)d_out;
    char* ws = (char*)d_ws;

    constexpr size_t CTRL_OFF  = 0;                          // 256 B
    constexpr size_t WTHI_OFF  = 256;                        // 196608 B
    constexpr size_t MASKC_OFF = WTHI_OFF + 196608;          // 34560 B -> ends 231424
    constexpr size_t SSQ_OFF   = 231424;                     // 147456 B
    constexpr size_t X_OFF     = SSQ_OFF + 147456;           // 19415040 B
    constexpr size_t QFRAG_OFF = X_OFF + (size_t)NROWS * D_ * 4;   // 983040 B
    constexpr size_t PFRAG_OFF = QFRAG_OFF + 983040;         // 9437184 B

    unsigned int* ctrl     = (unsigned int*)(ws + CTRL_OFF);
    unsigned short* wthi   = (unsigned short*)(ws + WTHI_OFF);
    unsigned char* maskc   = (unsigned char*)(ws + MASKC_OFF);
    float* ssq             = (float*)(ws + SSQ_OFF);
    float* x               = (float*)(ws + X_OFF);
    unsigned short* qfrag  = (unsigned short*)(ws + QFRAG_OFF);
    unsigned short* pfrag  = (unsigned short*)(ws + PFRAG_OFF);

    prep_k<<<193, 256, 0, stream>>>(W, wthi, (const unsigned int*)pmask, ctrl, ssq);
    proj_k<<<1185 + 135, 256, 0, stream>>>(qh, ph, nh, wthi, bias, x, ssq,
                                           pmask, nmask, ctrl, maskc);
    scatter_k<<<2544, 256, 0, stream>>>(x, ssq, maskc, qfrag, pfrag);
    interact_k<<<2304, 256, 0, stream>>>(qfrag, pfrag, out);
}

// Round 10
// 197.983 us; speedup vs baseline: 1.1111x; 1.0226x over previous
//
#include <hip/hip_runtime.h>

typedef __attribute__((ext_vector_type(4))) float f32x4;
typedef __attribute__((ext_vector_type(8))) short s16x8;
typedef __attribute__((ext_vector_type(4))) short s16x4;
typedef __bf16 bf16x4 __attribute__((ext_vector_type(4)));

#define B_   96
#define NQ   35
#define LP   180
#define H_   768
#define D_   128
#define NEGF (-1e30f)

#define NROWS 37920
#define QROWS 3360
#define PROWS 17280

__device__ __forceinline__ unsigned short f2bf(float f) {
    return __builtin_bit_cast(unsigned short, (__bf16)f);
}

__device__ __forceinline__ s16x4 cvt_bf4(f32x4 v) {
    return __builtin_bit_cast(s16x4, __builtin_convertvector(v, bf16x4));
}

__device__ __forceinline__ s16x8 pack_bf16(f32x4 v0, f32x4 v1) {
    bf16x4 h0 = __builtin_convertvector(v0, bf16x4);
    bf16x4 h1 = __builtin_convertvector(v1, bf16x4);
    s16x4 a = __builtin_bit_cast(s16x4, h0), b = __builtin_bit_cast(s16x4, h1);
    return __builtin_shufflevector(a, b, 0, 1, 2, 3, 4, 5, 6, 7);
}

// async global->LDS, 16 B per lane; lds dest must be wave-uniform (HW adds lane*16)
__device__ __forceinline__ void glds16(const void* g, void* l) {
    __builtin_amdgcn_global_load_lds(
        (const __attribute__((address_space(1))) unsigned int*)g,
        (__attribute__((address_space(3))) unsigned int*)l,
        16, 0, 0);
}

// ---------------- prep: wt_build (blocks 0-47) + ssq zero (48-191) + mask detect (192) ----
__global__ __launch_bounds__(256) void prep_k(
    const float* __restrict__ W, unsigned short* __restrict__ wthi,
    const unsigned int* __restrict__ pmask_w, unsigned int* __restrict__ ctrl,
    float* __restrict__ ssq) {
    __shared__ unsigned int rr[256];
    int b = blockIdx.x, t = threadIdx.x;
    if (b < 48) {
        int tid = b * 256 + t;
        int nt = tid / (24 * 64);
        int r = tid - nt * 24 * 64;
        int ks = r / 64, lane = r - ks * 64;
        int m = lane & 15, quad = lane >> 4;
        unsigned short* o = wthi + (size_t)tid * 8;
#pragma unroll
        for (int j = 0; j < 8; j++) {
            int k = ks * 32 + quad * 8 + j;
            o[j] = f2bf(W[(size_t)k * D_ + nt * 16 + m]);
        }
    } else if (b < 192) {
        ssq[(b - 48) * 256 + t] = 0.f;       // 144*256 = 36864 exactly
    } else {
        unsigned int f1 = 0, f3 = 0, f4 = 0;
        for (int w = t; w < 4320; w += 256) {
            unsigned int v = pmask_w[w];
            f1 |= v & 0x0000ff00u;                 // byte %4==1 -> 1-byte layout
            f3 |= v & 0xff000000u;                 // byte %4==3 -> float32
            if (w & 1) f4 |= v & 0x000000ffu;      // byte %8==4 -> int32
        }
        rr[t] = f1; __syncthreads();
        for (int s2 = 128; s2; s2 >>= 1) { if (t < s2) rr[t] |= rr[t + s2]; __syncthreads(); }
        if (!t) ctrl[0] = rr[0];
        __syncthreads();
        rr[t] = f3; __syncthreads();
        for (int s2 = 128; s2; s2 >>= 1) { if (t < s2) rr[t] |= rr[t + s2]; __syncthreads(); }
        if (!t) ctrl[1] = rr[0];
        __syncthreads();
        rr[t] = f4; __syncthreads();
        for (int s2 = 128; s2; s2 >>= 1) { if (t < s2) rr[t] |= rr[t + s2]; __syncthreads(); }
        if (!t) ctrl[2] = rr[0];
    }
}

// ---------------- proj v3: dense A stream, bf16-on-write LDS transpose, hi-only ---------
// Block = 32 rows x 128 cols x full K. Per step (BK=64): thread t loads rows (t>>4) and
// 16+(t>>4), 16 contiguous bytes (dense stream), converts to bf16 and stores 8 B into a
// padded LDS layout [mt][ksg][row(stride 80B)][kk]. Inner loop: ds_read_b128 + MFMA only.
// A is bf16 (hi-only): the normalized output is rounded to bf16 in scatter anyway, and
// W is already hi-only (R1->R2 showed no absmax change). Epilogue fuses x + ssq atomics.
__global__ __launch_bounds__(256) void proj_k(
    const float* __restrict__ qh, const float* __restrict__ ph, const float* __restrict__ nh,
    const unsigned short* __restrict__ wthi, const float* __restrict__ bias,
    float* __restrict__ x, float* __restrict__ ssq,
    const void* __restrict__ pm, const void* __restrict__ nm,
    const unsigned int* __restrict__ ctrl, unsigned char* __restrict__ maskc) {
    // ushort units: row stride 40 (80 B), ksg stride 640, mt stride 1280, buf stride 2560
    __shared__ unsigned short sh[5120];              // 10240 B
    int b = blockIdx.x;
    if (b >= 1185) {                                 // ---- mask canon: 135 blocks exact ----
        int i = (b - 1185) * 256 + threadIdx.x;      // < 34560
        const void* src = (i < B_ * LP) ? pm : nm;
        int j = (i < B_ * LP) ? i : i - B_ * LP;
        unsigned int c1 = ctrl[0], c3 = ctrl[1], c4 = ctrl[2];
        bool bit;
        if (c1 > 0)       bit = ((const unsigned char*)src)[j] != 0;
        else if (c3 > 0)  bit = ((const float*)src)[j] != 0.0f;
        else if (c4 > 0)  bit = ((const int*)src)[j] != 0;
        else              bit = ((const long long*)src)[j] != 0;
        maskc[i] = bit ? 1 : 0;
        return;
    }
    int t = threadIdx.x;
    int wave = t >> 6, lane = t & 63;
    const float* src; int row0l; int growbase;
    if (b < 105)      { src = qh; row0l = b * 32;         growbase = row0l; }
    else if (b < 645) { src = ph; row0l = (b - 105) * 32; growbase = QROWS + row0l; }
    else              { src = nh; row0l = (b - 645) * 32; growbase = QROWS + PROWS + row0l; }
    int m = lane & 15, quad = lane >> 4;

    // staging roles: thread t -> rows (t>>4), 16+(t>>4); 16 B k-chunk c = t&15
    int srow = t >> 4, c = t & 15;
    int sksg = c >> 3, kk = c & 7;
    int woff0 = sksg * 640 + srow * 40 + kk * 4;     // mt = 0
    int woff1 = woff0 + 1280;                        // mt = 1
    int roff = m * 40 + quad * 8;                    // + ksg*640 + mt*1280 + buf*2560
    const float* gp0 = src + (size_t)(row0l + srow) * H_ + c * 4;
    const float* gp1 = gp0 + (size_t)16 * H_;

    f32x4 acc[2][2];
#pragma unroll
    for (int mt = 0; mt < 2; mt++)
#pragma unroll
        for (int ntl = 0; ntl < 2; ntl++) acc[mt][ntl] = (f32x4){0.f, 0.f, 0.f, 0.f};

    int nt0 = wave * 2, nt1 = wave * 2 + 1;

    f32x4 pv0 = *(const f32x4*)gp0;                  // prefetch step 0
    f32x4 pv1 = *(const f32x4*)gp1;

#pragma unroll 2
    for (int s = 0; s < 12; s++) {
        int bufo = (s & 1) * 2560;
        *(s16x4*)&sh[bufo + woff0] = cvt_bf4(pv0);
        *(s16x4*)&sh[bufo + woff1] = cvt_bf4(pv1);
        __syncthreads();
        if (s < 11) {
            pv0 = *(const f32x4*)(gp0 + (s + 1) * 64);
            pv1 = *(const f32x4*)(gp1 + (s + 1) * 64);
        }
#pragma unroll
        for (int ksg = 0; ksg < 2; ksg++) {
            int ksgg = s * 2 + ksg;
            s16x8 a0 = *(const s16x8*)&sh[bufo + ksg * 640 + roff];
            s16x8 a1 = *(const s16x8*)&sh[bufo + ksg * 640 + 1280 + roff];
            s16x8 bh0 = *(const s16x8*)(wthi + ((size_t)(nt0 * 24 + ksgg) * 64 + lane) * 8);
            s16x8 bh1 = *(const s16x8*)(wthi + ((size_t)(nt1 * 24 + ksgg) * 64 + lane) * 8);
            acc[0][0] = __builtin_amdgcn_mfma_f32_16x16x32_bf16(a0, bh0, acc[0][0], 0, 0, 0);
            acc[0][1] = __builtin_amdgcn_mfma_f32_16x16x32_bf16(a0, bh1, acc[0][1], 0, 0, 0);
            acc[1][0] = __builtin_amdgcn_mfma_f32_16x16x32_bf16(a1, bh0, acc[1][0], 0, 0, 0);
            acc[1][1] = __builtin_amdgcn_mfma_f32_16x16x32_bf16(a1, bh1, acc[1][1], 0, 0, 0);
        }
    }

    // epilogue: x write + fused ssq (wave owns cols [wave*32, wave*32+32), all 32 rows)
#pragma unroll
    for (int mt = 0; mt < 2; mt++) {
        int base = growbase + mt * 16;
        int bk0, bk1, b1start;
        if (base < QROWS)              { bk0 = base / 35;  bk1 = (base + 15) / 35;
                                         b1start = bk1 * 35; }
        else if (base < QROWS + PROWS) { int r0 = base - QROWS;
                                         bk0 = 96 + r0 / 180;  bk1 = 96 + (r0 + 15) / 180;
                                         b1start = QROWS + (bk1 - 96) * 180; }
        else                           { int r0 = base - QROWS - PROWS;
                                         bk0 = 192 + r0 / 180; bk1 = 192 + (r0 + 15) / 180;
                                         b1start = QROWS + PROWS + (bk1 - 192) * 180; }
#pragma unroll
        for (int ntl = 0; ntl < 2; ntl++) {
            int col = (wave * 2 + ntl) * 16 + m;
            float bv = bias[col];
            f32x4 s4 = acc[mt][ntl];
            float slo = 0.f, shi = 0.f;
#pragma unroll
            for (int r = 0; r < 4; r++) {
                int grow = base + quad * 4 + r;
                float v = s4[r] + bv;
                x[(size_t)grow * D_ + col] = v;
                float v2 = v * v;
                if (bk1 > bk0 && grow >= b1start) shi += v2; else slo += v2;
            }
            slo += __shfl_xor(slo, 16); slo += __shfl_xor(slo, 32);
            if (quad == 0) atomicAdd(ssq + (size_t)bk0 * D_ + col, slo);
            if (bk1 > bk0) {
                shi += __shfl_xor(shi, 16); shi += __shfl_xor(shi, 32);
                if (quad == 0) atomicAdd(ssq + (size_t)bk1 * D_ + col, shi);
            }
        }
    }
}

// ---------------- scale + bf16 + scatter: one thread per 16B frag chunk -----------------
__global__ __launch_bounds__(256) void scatter_k(
    const float* __restrict__ x, const float* __restrict__ ssq,
    const unsigned char* __restrict__ maskc,
    unsigned short* __restrict__ qfrag, unsigned short* __restrict__ pfrag) {
    int c = blockIdx.x * 256 + threadIdx.x;          // 651264 total = 2544*256
    int lane = c & 63, ks = (c >> 6) & 3;
    int quad = lane >> 4, mm = lane & 15;
    int d0 = ks * 32 + quad * 8;
    if (c < 61440) {
        int g = c >> 8;                              // qp*5 + mt
        int mt = g % 5, qp = g / 5;
        int prow = mt * 16 + mm;
        s16x8 outv = (s16x8){0, 0, 0, 0, 0, 0, 0, 0};
        if (prow < 70) {
            int hi = prow >= 35;
            int bq = qp * 2 + hi;
            int l = prow - hi * 35;
            size_t row = (size_t)bq * 35 + l;
            const f32x4* px = (const f32x4*)(x + row * D_ + d0);
            f32x4 v0 = px[0], v1 = px[1];
            const f32x4* pq = (const f32x4*)(ssq + (size_t)bq * D_ + d0);
            f32x4 q0 = pq[0], q1 = pq[1];
            f32x4 r0, r1;
#pragma unroll
            for (int j = 0; j < 4; j++) {
                r0[j] = rsqrtf(fmaxf(q0[j], 1e-24f));
                r1[j] = rsqrtf(fmaxf(q1[j], 1e-24f));
            }
            outv = pack_bf16(v0 * r0, v1 * r1);
        }
        *(s16x8*)(qfrag + (size_t)c * 8) = outv;
    } else {
        int c2 = c - 61440;
        int g = c2 >> 8;                             // pbk*12 + nt
        int nt = g % 12, pbk = g / 12;
        int l = nt * 16 + mm;
        int lsrc = (l < LP && maskc[pbk * LP + l]) ? l : 0;
        size_t row = QROWS + (size_t)pbk * LP + lsrc;
        const f32x4* px = (const f32x4*)(x + row * D_ + d0);
        f32x4 v0 = px[0], v1 = px[1];
        const f32x4* pq = (const f32x4*)(ssq + (size_t)(96 + pbk) * D_ + d0);
        f32x4 q0 = pq[0], q1 = pq[1];
        f32x4 r0, r1;
#pragma unroll
        for (int j = 0; j < 4; j++) {
            r0[j] = rsqrtf(fmaxf(q0[j], 1e-24f));
            r1[j] = rsqrtf(fmaxf(q1[j], 1e-24f));
        }
        *(s16x8*)(pfrag + (size_t)c2 * 8) = pack_bf16(v0 * r0, v1 * r1);
    }
}

// ---------------- late interaction: p-block staged via glds, XCD-pinned, mask-free ------
__global__ __launch_bounds__(256, 3) void interact_k(
    const unsigned short* __restrict__ qfrag, const unsigned short* __restrict__ pfrag,
    float* __restrict__ out) {
    __shared__ unsigned short plds[24576];           // 48 KB, shared by all 4 waves
    int wave = threadIdx.x >> 6, lane = threadIdx.x & 63;
    int b = blockIdx.x;                              // 2304 blocks
    int xcd = b & 7, i = b >> 3;                     // i in [0,288)
    int c = xcd * 24 + (i % 24);                     // [0,192)
    int qg = i / 24;                                 // [0,12)
    int side = c / 96, pb = c - side * 96;
    int qp = qg * 4 + wave;
    int m = lane & 15, quad = lane >> 4;

    const unsigned short* pbase = pfrag + (size_t)c * 24576;
    const unsigned short* qbase = qfrag + (size_t)qp * 10240;

#pragma unroll
    for (int ntl = 0; ntl < 3; ntl++) {
        int nt = wave * 3 + ntl;
#pragma unroll
        for (int ks = 0; ks < 4; ks++)
            glds16(pbase + ((size_t)(nt * 4 + ks) * 64 + lane) * 8,
                   &plds[(size_t)(nt * 4 + ks) * 512]);
    }

    s16x8 a[5][4];
#pragma unroll
    for (int mt = 0; mt < 5; mt++)
#pragma unroll
        for (int ks = 0; ks < 4; ks++)
            a[mt][ks] = *(const s16x8*)(qbase + ((size_t)(mt * 4 + ks) * 64 + lane) * 8);

    __syncthreads();                                 // drain staging

    const f32x4 zero4 = (f32x4){0.f, 0.f, 0.f, 0.f};
    float rmax[5][4];
#pragma unroll
    for (int mt = 0; mt < 5; mt++)
#pragma unroll
        for (int rr = 0; rr < 4; rr++) rmax[mt][rr] = NEGF;

    for (int nt = 0; nt < 12; nt++) {
        s16x8 bfr[4];
#pragma unroll
        for (int ks = 0; ks < 4; ks++)
            bfr[ks] = *(const s16x8*)&plds[((size_t)(nt * 4 + ks) * 64 + lane) * 8];
#pragma unroll
        for (int mt = 0; mt < 5; mt++) {
            f32x4 acc = __builtin_amdgcn_mfma_f32_16x16x32_bf16(a[mt][0], bfr[0], zero4, 0, 0, 0);
            acc = __builtin_amdgcn_mfma_f32_16x16x32_bf16(a[mt][1], bfr[1], acc, 0, 0, 0);
            acc = __builtin_amdgcn_mfma_f32_16x16x32_bf16(a[mt][2], bfr[2], acc, 0, 0, 0);
            acc = __builtin_amdgcn_mfma_f32_16x16x32_bf16(a[mt][3], bfr[3], acc, 0, 0, 0);
#pragma unroll
            for (int rr = 0; rr < 4; rr++)
                rmax[mt][rr] = fmaxf(rmax[mt][rr], acc[rr]);
        }
    }

#pragma unroll
    for (int mt = 0; mt < 5; mt++)
#pragma unroll
        for (int rr = 0; rr < 4; rr++) {
            float v = rmax[mt][rr];
            v = fmaxf(v, __shfl_xor(v, 1));
            v = fmaxf(v, __shfl_xor(v, 2));
            v = fmaxf(v, __shfl_xor(v, 4));
            v = fmaxf(v, __shfl_xor(v, 8));
            rmax[mt][rr] = v;
        }
    float s0 = 0.f, s1 = 0.f;
#pragma unroll
    for (int mt = 0; mt < 5; mt++)
#pragma unroll
        for (int rr = 0; rr < 4; rr++) {
            int prow = mt * 16 + quad * 4 + rr;
            float v = rmax[mt][rr];
            if (prow < 35) s0 += v;
            else if (prow < 70) s1 += v;
        }
    s0 += __shfl_xor(s0, 16); s0 += __shfl_xor(s0, 32);
    s1 += __shfl_xor(s1, 16); s1 += __shfl_xor(s1, 32);
    if (lane == 0) {
        int qb0 = qp * 2, qb1 = qp * 2 + 1;
        out[(size_t)qb0 * (2 * B_) + side * B_ + pb] = s0;
        out[(size_t)qb1 * (2 * B_) + side * B_ + pb] = s1;
    }
}

// ---------------- launch ----------------
extern "C" void kernel_launch(void* const* d_in, const int* in_sizes, int n_in,
                              void* d_out, int out_size, void* d_ws, size_t ws_size,
                              hipStream_t stream) {
    const float* qh   = (const float*)d_in[0];
    const float* ph   = (const float*)d_in[1];
    const float* nh   = (const float*)d_in[2];
    const float* W    = (const float*)d_in[3];
    const float* bias = (const float*)d_in[4];
    const void* pmask = d_in[5];
    const void* nmask = d_in[6];
    float* out = (float*)d_out;
    char* ws = (char*)d_ws;

    constexpr size_t CTRL_OFF  = 0;                          // 256 B
    constexpr size_t WTHI_OFF  = 256;                        // 196608 B
    constexpr size_t MASKC_OFF = WTHI_OFF + 196608;          // 34560 B -> ends 231424
    constexpr size_t SSQ_OFF   = 231424;                     // 147456 B
    constexpr size_t X_OFF     = SSQ_OFF + 147456;           // 19415040 B
    constexpr size_t QFRAG_OFF = X_OFF + (size_t)NROWS * D_ * 4;   // 983040 B
    constexpr size_t PFRAG_OFF = QFRAG_OFF + 983040;         // 9437184 B

    unsigned int* ctrl     = (unsigned int*)(ws + CTRL_OFF);
    unsigned short* wthi   = (unsigned short*)(ws + WTHI_OFF);
    unsigned char* maskc   = (unsigned char*)(ws + MASKC_OFF);
    float* ssq             = (float*)(ws + SSQ_OFF);
    float* x               = (float*)(ws + X_OFF);
    unsigned short* qfrag  = (unsigned short*)(ws + QFRAG_OFF);
    unsigned short* pfrag  = (unsigned short*)(ws + PFRAG_OFF);

    prep_k<<<193, 256, 0, stream>>>(W, wthi, (const unsigned int*)pmask, ctrl, ssq);
    proj_k<<<1185 + 135, 256, 0, stream>>>(qh, ph, nh, wthi, bias, x, ssq,
                                           pmask, nmask, ctrl, maskc);
    scatter_k<<<2544, 256, 0, stream>>>(x, ssq, maskc, qfrag, pfrag);
    interact_k<<<2304, 256, 0, stream>>>(qfrag, pfrag, out);
}